// Round 5
// baseline (1488.028 us; speedup 1.0000x reference)
//
#include <hip/hip_runtime.h>

__device__ __forceinline__ float sigmoidf_(float x) { return 1.f / (1.f + __expf(-x)); }
__device__ __forceinline__ unsigned bf16rne(float x) {
    unsigned b = __float_as_uint(x);
    return (b + 0x7FFFu + ((b >> 16) & 1u)) >> 16;
}

// ws layout (float words):
//   OFFM:  lvl0 @0 (2359296), lvl1 @2359296 (589824), lvl2 @2949120 (147456)
//   MOD:   lvl0 @3096576 (1179648), lvl1 @4276224 (294912), lvl2 @4571136 (73728)
//   MEAN:  lvl0 @4644864 (65536), lvl1 @4710400 (16384), lvl2 @4726784 (4096)
//   WREP:  @4730880, 3*62784 (per lvl: [36864 reg][5184 off][20736 mod])
//   S:     @4919232 (uints), lvl0 +0 (9437184), lvl1 +9437184 (2359296), lvl2 +11796480 (589824)
// XT lives in d_out's feat region (consumed in K2, overwritten in K3):
//   lvl0 @out+655360, lvl1 @out+131072, lvl2 @out+0

struct P {
    const float *sou0, *sou1, *sou2;
    const float *ref0, *ref1, *ref2;
    const float *ob0, *ob1, *ob2;
    const float *mb0, *mb1, *mb2;
    float* out;
    float* ws;
};

// ---------------- K0: fused weight repack (all levels) --------------------------------
__global__ __launch_bounds__(256) void repack_all(
    const float* __restrict__ ow0, const float* __restrict__ mw0, const float* __restrict__ rw0,
    const float* __restrict__ ow1, const float* __restrict__ mw1, const float* __restrict__ rw1,
    const float* __restrict__ ow2, const float* __restrict__ mw2, const float* __restrict__ rw2,
    float* __restrict__ dst) {
    const int lvl = blockIdx.y;
    const float* ow = lvl == 0 ? ow0 : (lvl == 1 ? ow1 : ow2);
    const float* mw = lvl == 0 ? mw0 : (lvl == 1 ? mw1 : mw2);
    const float* rw = lvl == 0 ? rw0 : (lvl == 1 ? rw1 : rw2);
    float* d = dst + lvl * 62784;
    int i = blockIdx.x * 256 + threadIdx.x;
    if (i < 36864) {  // reg -> [g][k][c16][o64]
        int o = i % 64, c = (i / 64) % 16, k = (i / 1024) % 9, g = i / 9216;
        d[i] = rw[o * 576 + (g * 16 + c) * 9 + k];
    }
    if (i < 5184) {   // off -> [ic][k][18]
        int oc = i % 18, k = (i / 18) % 9, ic = i / 162;
        d[36864 + i] = ow[oc * 288 + ic * 9 + k];
    }
    if (i < 20736) {  // mod -> [ic][k][36]
        int oc = i % 36, k = (i / 36) % 9, ic = i / 324;
        d[42048 + i] = mw[oc * 576 + ic * 9 + k];
    }
}

// ---------------- K1: offset_conv(672) + mod_conv(672) + transpose(672) ---------------
// __launch_bounds__(256,6): cap ~85 VGPR -> 6 blocks/CU (24 waves). R4's 188 VGPR
// (from unroll-2 + branch union) capped residency at ~2 blocks/CU -> 10.5% occ.
__global__ __launch_bounds__(256, 6) void k1_prep(P p) {
    __shared__ float tile[256][17];
    const int t = blockIdx.x;
    int task, i;
    if (t < 672) { task = 0; i = t; }
    else if (t < 1344) { task = 1; i = t - 672; }
    else { task = 2; i = t - 1344; }
    int lvl, j;
    if (i < 512) { lvl = 0; j = i; }
    else if (i < 640) { lvl = 1; j = i - 512; }
    else { lvl = 2; j = i - 640; }
    const int logW = 7 - lvl;
    const int W = 1 << logW, H = W, HW = H * W;
    const float* sou = lvl == 0 ? p.sou0 : (lvl == 1 ? p.sou1 : p.sou2);
    float* ws = p.ws;
    float* OFFM = ws + (lvl == 0 ? 0 : (lvl == 1 ? 2359296 : 2949120));
    float* MOD = ws + (lvl == 0 ? 3096576 : (lvl == 1 ? 4276224 : 4571136));
    const float* WREP = ws + 4730880 + lvl * 62784;
    float* XT = p.out + (lvl == 0 ? 655360 : (lvl == 1 ? 131072 : 0));

    if (task == 0) {  // ---- offset conv: 32ch(concat) -> 18, sigmoid map
        const int nper = 64 >> (2 * lvl);
        const int qb = j % nper, g = (j / nper) & 3, b = j / (nper * 4);
        const int q = qb * 256 + threadIdx.x;
        const int h = q >> logW, x = q & (W - 1);
        const float* ref = lvl == 0 ? p.ref0 : (lvl == 1 ? p.ref1 : p.ref2);
        const float* wt = WREP + 36864;
        const float* bias = lvl == 0 ? p.ob0 : (lvl == 1 ? p.ob1 : p.ob2);
        const float rng = 0.25f * (float)H;
        float acc[18];
#pragma unroll
        for (int u = 0; u < 18; ++u) acc[u] = 0.f;
        const float* base_s = sou + (size_t)(b * 64 + g * 16) * HW;
        const float* base_r = ref + (size_t)(b * 64 + g * 16) * HW;
        for (int ic = 0; ic < 32; ++ic) {
            const float* plane = (ic < 16) ? base_s + (size_t)ic * HW : base_r + (size_t)(ic - 16) * HW;
            const float* wp = wt + ic * 162;
#pragma unroll
            for (int ky = 0; ky < 3; ++ky) {
                int yy = h + ky - 1;
                bool yok = (yy >= 0) && (yy < H);
                const float* row = plane + (size_t)min(max(yy, 0), H - 1) * W;
#pragma unroll
                for (int kx = 0; kx < 3; ++kx) {
                    int xx = x + kx - 1;
                    bool ok = yok && (xx >= 0) && (xx < W);
                    float v = ok ? row[min(max(xx, 0), W - 1)] : 0.f;
                    const float* wk = wp + (ky * 3 + kx) * 18;
#pragma unroll
                    for (int oc = 0; oc < 18; ++oc) acc[oc] = fmaf(v, wk[oc], acc[oc]);
                }
            }
        }
#pragma unroll
        for (int oc = 0; oc < 18; ++oc) {
            float v = acc[oc] + bias[oc];
            OFFM[(size_t)(b * 72 + g * 18 + oc) * HW + q] = rng * (2.f * sigmoidf_(v) - 1.f);
        }
    } else if (task == 1) {  // ---- modulator conv: 64 -> 36, 2*sigmoid, oc split by wave
        const int nper = 256 >> (2 * lvl);
        const int qb = j % nper, b = j / nper;
        const int o0 = __builtin_amdgcn_readfirstlane((int)threadIdx.x >> 6) * 9;
        const int lane = threadIdx.x & 63;
        const int q = qb * 64 + lane;
        const int h = q >> logW, x = q & (W - 1);
        const float* wt = WREP + 42048;
        const float* bias = lvl == 0 ? p.mb0 : (lvl == 1 ? p.mb1 : p.mb2);
        float acc[9];
#pragma unroll
        for (int u = 0; u < 9; ++u) acc[u] = 0.f;
        const float* base = sou + (size_t)b * 64 * HW;
        for (int ic = 0; ic < 64; ++ic) {
            const float* plane = base + (size_t)ic * HW;
            const float* wp = wt + ic * 324 + o0;
#pragma unroll
            for (int ky = 0; ky < 3; ++ky) {
                int yy = h + ky - 1;
                bool yok = (yy >= 0) && (yy < H);
                const float* row = plane + (size_t)min(max(yy, 0), H - 1) * W;
#pragma unroll
                for (int kx = 0; kx < 3; ++kx) {
                    int xx = x + kx - 1;
                    bool ok = yok && (xx >= 0) && (xx < W);
                    float v = ok ? row[min(max(xx, 0), W - 1)] : 0.f;
                    const float* wk = wp + (ky * 3 + kx) * 36;
#pragma unroll
                    for (int oc = 0; oc < 9; ++oc) acc[oc] = fmaf(v, wk[oc], acc[oc]);
                }
            }
        }
#pragma unroll
        for (int oc = 0; oc < 9; ++oc)
            MOD[(size_t)(b * 36 + o0 + oc) * HW + q] = 2.f * sigmoidf_(acc[oc] + bias[o0 + oc]);
    } else {  // ---- transpose (b,64,H,W) -> XT (b,g,HW,16)
        const int nper = 64 >> (2 * lvl);
        const int qb = j % nper, g = (j / nper) & 3, b = j / (nper * 4);
        const int tt = threadIdx.x;
        const int q0 = qb * 256;
        const float* src = sou + (size_t)(b * 64 + g * 16) * HW + q0;
#pragma unroll
        for (int c = 0; c < 16; ++c) tile[tt][c] = src[(size_t)c * HW + tt];
        __syncthreads();
        float4* dst = (float4*)(XT + ((size_t)(b * 4 + g) * HW + q0) * 16);
#pragma unroll
        for (int u = 0; u < 4; ++u) {
            int f4 = u * 256 + tt;
            int q = f4 >> 2, c4 = (f4 & 3) * 4;
            dst[f4] = make_float4(tile[q][c4], tile[q][c4 + 1], tile[q][c4 + 2], tile[q][c4 + 3]);
        }
    }
}

// ---------------- K2: gather(6048) + mean(168) ----------------------------------------
__global__ __launch_bounds__(256) void k2_gather(P p) {
    const int t = blockIdx.x;
    float* ws = p.ws;
    if (t < 6048) {
        int lvl, j;
        if (t < 4608) { lvl = 0; j = t; }
        else if (t < 5760) { lvl = 1; j = t - 4608; }
        else { lvl = 2; j = t - 5760; }
        const int logW = 7 - lvl;
        const int W = 1 << logW, H = W, HW = H * W;
        const int nper = 64 >> (2 * lvl);
        const int qb = j % nper, gk = (j / nper) % 36, b = j / (nper * 36);
        const int g = gk / 9, k = gk - g * 9;
        const float* OFFM = ws + (lvl == 0 ? 0 : (lvl == 1 ? 2359296 : 2949120));
        const float* MOD = ws + (lvl == 0 ? 3096576 : (lvl == 1 ? 4276224 : 4571136));
        const float* XT = p.out + (lvl == 0 ? 655360 : (lvl == 1 ? 131072 : 0));
        unsigned* S = (unsigned*)(ws + 4919232) + (lvl == 0 ? 0 : (lvl == 1 ? 9437184 : 11796480));
        const int q = qb * 256 + threadIdx.x;
        const int h = q >> logW, xp = q & (W - 1);
        const int ky = k / 3, kx = k - ky * 3;
        float dy = OFFM[(size_t)(b * 72 + g * 18 + 2 * k) * HW + q];
        float dx = OFFM[(size_t)(b * 72 + g * 18 + 2 * k + 1) * HW + q];
        float m = MOD[(size_t)(b * 36 + g * 9 + k) * HW + q];
        float py = (float)(h - 1 + ky) + dy;
        float px = (float)(xp - 1 + kx) + dx;
        float y0f = floorf(py), x0f = floorf(px);
        float wy = py - y0f, wx = px - x0f;
        int y0 = (int)y0f, x0 = (int)x0f;
        const float* xg = XT + (size_t)(b * 4 + g) * HW * 16;
        float s[16];
#pragma unroll
        for (int c = 0; c < 16; ++c) s[c] = 0.f;
#pragma unroll
        for (int cor = 0; cor < 4; ++cor) {
            int yy = y0 + (cor >> 1), xx = x0 + (cor & 1);
            float cw = ((cor >> 1) ? wy : 1.f - wy) * ((cor & 1) ? wx : 1.f - wx);
            cw = (yy >= 0 && yy < H && xx >= 0 && xx < W) ? cw * m : 0.f;
            int yc = min(max(yy, 0), H - 1), xc = min(max(xx, 0), W - 1);
            const float4* pp = (const float4*)(xg + (size_t)((yc << logW) + xc) * 16);
            float4 v0 = pp[0], v1 = pp[1], v2 = pp[2], v3 = pp[3];
            s[0] = fmaf(cw, v0.x, s[0]);   s[1] = fmaf(cw, v0.y, s[1]);
            s[2] = fmaf(cw, v0.z, s[2]);   s[3] = fmaf(cw, v0.w, s[3]);
            s[4] = fmaf(cw, v1.x, s[4]);   s[5] = fmaf(cw, v1.y, s[5]);
            s[6] = fmaf(cw, v1.z, s[6]);   s[7] = fmaf(cw, v1.w, s[7]);
            s[8] = fmaf(cw, v2.x, s[8]);   s[9] = fmaf(cw, v2.y, s[9]);
            s[10] = fmaf(cw, v2.z, s[10]); s[11] = fmaf(cw, v2.w, s[11]);
            s[12] = fmaf(cw, v3.x, s[12]); s[13] = fmaf(cw, v3.y, s[13]);
            s[14] = fmaf(cw, v3.z, s[14]); s[15] = fmaf(cw, v3.w, s[15]);
        }
        unsigned* Sp = S + (size_t)(b * 288 + gk * 8) * HW + q;
#pragma unroll
        for (int pr = 0; pr < 8; ++pr) {
            unsigned u = bf16rne(s[2 * pr]) | (bf16rne(s[2 * pr + 1]) << 16);
            Sp[(size_t)pr * HW] = u;
        }
    } else {
        int i = t - 6048;
        int lvl, j;
        if (i < 128) { lvl = 0; j = i; }
        else if (i < 160) { lvl = 1; j = i - 128; }
        else { lvl = 2; j = i - 160; }
        const int HW = 16384 >> (2 * lvl);
        const int nper = 64 >> (2 * lvl);
        const int qb = j % nper, b = j / nper;
        const float* OFFM = ws + (lvl == 0 ? 0 : (lvl == 1 ? 2359296 : 2949120));
        float* MEAN = ws + (lvl == 0 ? 4644864 : (lvl == 1 ? 4710400 : 4726784));
        const int q = qb * 256 + threadIdx.x;
        const float* pp = OFFM + (size_t)b * 72 * HW + q;
        float sy = 0.f, sx = 0.f;
#pragma unroll
        for (int u = 0; u < 36; ++u) {
            sy += pp[(size_t)(2 * u) * HW];
            sx += pp[(size_t)(2 * u + 1) * HW];
        }
        MEAN[(size_t)(b * 2) * HW + q] = sy * (1.f / 36.f);
        MEAN[(size_t)(b * 2 + 1) * HW + q] = sx * (1.f / 36.f);
    }
}

// ---------------- K3: dgemm(672, 2x144-row LDS chunks) + upsample(3072) ---------------
__global__ __launch_bounds__(256, 4) void k3_out(P p) {
    __shared__ unsigned lds[144 * 64];  // 36 KB -> 4 blocks/CU (was 72 KB -> 2)
    const int t = blockIdx.x;
    float* ws = p.ws;
    if (t < 672) {
        int lvl, j;
        if (t < 512) { lvl = 0; j = t; }
        else if (t < 640) { lvl = 1; j = t - 512; }
        else { lvl = 2; j = t - 640; }
        const int HW = 16384 >> (2 * lvl);
        const int nper = 256 >> (2 * lvl);
        const int qb = j % nper, b = j / nper;
        const unsigned* S = (const unsigned*)(ws + 4919232) +
                            (lvl == 0 ? 0 : (lvl == 1 ? 9437184 : 11796480));
        const float* wt = ws + 4730880 + lvl * 62784;
        float* outp = p.out + (lvl == 0 ? 655360 : (lvl == 1 ? 131072 : 0));
        const int q0 = qb * 64;
        const int tid = threadIdx.x;
        const int wvu = __builtin_amdgcn_readfirstlane(tid >> 6);
        const int lane = tid & 63;
        float acc[16];
#pragma unroll
        for (int o = 0; o < 16; ++o) acc[o] = 0.f;
        for (int chk = 0; chk < 2; ++chk) {
            __syncthreads();
            const unsigned* Sb = S + (size_t)(b * 288 + chk * 144) * HW + q0;
            for (int i = tid; i < 144 * 16; i += 256) {
                int r = i >> 4, ch = (i & 15) << 2;
                *(uint4*)&lds[r * 64 + ch] = *(const uint4*)(Sb + (size_t)r * HW + ch);
            }
            __syncthreads();
            const float* wbase = wt + chk * 144 * 128 + wvu * 16;
#pragma unroll 2
            for (int r = 0; r < 144; ++r) {
                unsigned u = lds[r * 64 + lane];
                float flo = __uint_as_float(u << 16);
                float fhi = __uint_as_float(u & 0xFFFF0000u);
                const float* wp = wbase + r * 128;
#pragma unroll
                for (int o = 0; o < 16; ++o) acc[o] = fmaf(flo, wp[o], acc[o]);
#pragma unroll
                for (int o = 0; o < 16; ++o) acc[o] = fmaf(fhi, wp[64 + o], acc[o]);
            }
        }
        float* op = outp + (size_t)(b * 64 + wvu * 16) * HW + q0 + lane;
#pragma unroll
        for (int o = 0; o < 16; ++o) op[(size_t)o * HW] = acc[o];
    } else {
        // upsample: 4 px/thread over flat [lvl][b][c][512][512]
        int i = t - 672;  // 0..3071
        int flat = (i * 256 + (int)threadIdx.x) * 4;
        int lvl = flat >> 20;
        int r = flat & 1048575;
        int b = r >> 19, c = (r >> 18) & 1;
        int pix = r & 262143;
        int yo = pix >> 9, xo = pix & 511;
        const int H = 128 >> lvl, W = H;
        const float* MEAN = ws + (lvl == 0 ? 4644864 : (lvl == 1 ? 4710400 : 4726784));
        const float* m = MEAN + (size_t)(b * 2 + c) * H * W;
        float* o = p.out + (lvl == 0 ? 4849664 : (lvl == 1 ? 3801088 : 2752512)) +
                   ((size_t)(b * 2 + c) * 512 + yo) * 512 + xo;
        const float fs = (float)(4 << lvl);
        const float sc = (float)(H - 1) * (1.f / 511.f);
        float sy = yo * sc;
        int y0 = min((int)sy, H - 2);
        float wy = sy - (float)y0;
        float rr[4];
#pragma unroll
        for (int u = 0; u < 4; ++u) {
            float sx = (float)(xo + u) * sc;
            int x0 = min((int)sx, W - 2);
            float wx = sx - (float)x0;
            float v00 = m[y0 * W + x0], v01 = m[y0 * W + x0 + 1];
            float v10 = m[(y0 + 1) * W + x0], v11 = m[(y0 + 1) * W + x0 + 1];
            float r0 = v00 * (1.f - wy) + v10 * wy;
            float r1 = v01 * (1.f - wy) + v11 * wy;
            rr[u] = (r0 * (1.f - wx) + r1 * wx) * fs;
        }
        *(float4*)o = make_float4(rr[0], rr[1], rr[2], rr[3]);
    }
}

extern "C" void kernel_launch(void* const* d_in, const int* in_sizes, int n_in,
                              void* d_out, int out_size, void* d_ws, size_t ws_size,
                              hipStream_t stream) {
    const float* fin[21];
    for (int i = 0; i < 21; ++i) fin[i] = (const float*)d_in[i];
    P p;
    if (in_sizes[1] == in_sizes[0]) {  // dict order sou1,ref1,sou2,ref2,sou3,ref3
        p.sou0 = fin[0]; p.ref0 = fin[1];
        p.sou1 = fin[2]; p.ref1 = fin[3];
        p.sou2 = fin[4]; p.ref2 = fin[5];
    } else {  // arg order
        p.sou0 = fin[0]; p.sou1 = fin[1]; p.sou2 = fin[2];
        p.ref0 = fin[3]; p.ref1 = fin[4]; p.ref2 = fin[5];
    }
    p.ob0 = fin[7]; p.mb0 = fin[9];
    p.ob1 = fin[12]; p.mb1 = fin[14];
    p.ob2 = fin[17]; p.mb2 = fin[19];
    p.out = (float*)d_out;
    p.ws = (float*)d_ws;

    repack_all<<<dim3(144, 3), 256, 0, stream>>>(
        fin[6], fin[8], fin[10], fin[11], fin[13], fin[15], fin[16], fin[18], fin[20],
        p.ws + 4730880);
    k1_prep<<<dim3(2016), 256, 0, stream>>>(p);
    k2_gather<<<dim3(6216), 256, 0, stream>>>(p);
    k3_out<<<dim3(3744), 256, 0, stream>>>(p);
}

// Round 6
// 930.647 us; speedup vs baseline: 1.5989x; 1.5989x over previous
//
#include <hip/hip_runtime.h>

__device__ __forceinline__ float sigmoidf_(float x) { return 1.f / (1.f + __expf(-x)); }
__device__ __forceinline__ unsigned bf16rne(float x) {
    unsigned b = __float_as_uint(x);
    return (b + 0x7FFFu + ((b >> 16) & 1u)) >> 16;
}

// ws layout (float words):
//   OFFM:  lvl0 @0 (2359296), lvl1 @2359296 (589824), lvl2 @2949120 (147456)
//   MOD:   lvl0 @3096576 (1179648), lvl1 @4276224 (294912), lvl2 @4571136 (73728)
//   MEAN:  lvl0 @4644864 (65536), lvl1 @4710400 (16384), lvl2 @4726784 (4096)
//   WREP:  @4730880, 3*62784 (per lvl: [36864 reg][5184 off][20736 mod])
//   S:     @4919232 (uints), lvl0 +0 (9437184), lvl1 +9437184 (2359296), lvl2 +11796480 (589824)
// XT lives in d_out's feat region (consumed in K2, overwritten in K3):
//   lvl0 @out+655360, lvl1 @out+131072, lvl2 @out+0

struct P {
    const float *sou0, *sou1, *sou2;
    const float *ref0, *ref1, *ref2;
    const float *ob0, *ob1, *ob2;
    const float *mb0, *mb1, *mb2;
    float* out;
    float* ws;
};

// ---------------- K0: fused weight repack (all levels) --------------------------------
__global__ __launch_bounds__(256) void repack_all(
    const float* __restrict__ ow0, const float* __restrict__ mw0, const float* __restrict__ rw0,
    const float* __restrict__ ow1, const float* __restrict__ mw1, const float* __restrict__ rw1,
    const float* __restrict__ ow2, const float* __restrict__ mw2, const float* __restrict__ rw2,
    float* __restrict__ dst) {
    const int lvl = blockIdx.y;
    const float* ow = lvl == 0 ? ow0 : (lvl == 1 ? ow1 : ow2);
    const float* mw = lvl == 0 ? mw0 : (lvl == 1 ? mw1 : mw2);
    const float* rw = lvl == 0 ? rw0 : (lvl == 1 ? rw1 : rw2);
    float* d = dst + lvl * 62784;
    int i = blockIdx.x * 256 + threadIdx.x;
    if (i < 36864) {  // reg -> [g][k][c16][o64]
        int o = i % 64, c = (i / 64) % 16, k = (i / 1024) % 9, g = i / 9216;
        d[i] = rw[o * 576 + (g * 16 + c) * 9 + k];
    }
    if (i < 5184) {   // off -> [ic][k][18]
        int oc = i % 18, k = (i / 18) % 9, ic = i / 162;
        d[36864 + i] = ow[oc * 288 + ic * 9 + k];
    }
    if (i < 20736) {  // mod -> [ic][k][36]
        int oc = i % 36, k = (i / 36) % 9, ic = i / 324;
        d[42048 + i] = mw[oc * 576 + ic * 9 + k];
    }
}

// ---------------- K1: offset_conv(672) + mod_conv(672) + transpose(672) ---------------
// __launch_bounds__(256,4): 128-VGPR cap, 4 blocks/CU. History: no bound + unroll2 ->
// 188 VGPR, 2 blk/CU, 10% occ (R4); bound=6 -> 40 VGPR, SPILLS, 4.7 GB scratch traffic
// (R5). Bodies need ~28-64 VGPR standalone (R3), so 128 cap = zero spill + 16 waves/CU.
__global__ __launch_bounds__(256, 4) void k1_prep(P p) {
    __shared__ float tile[256][17];
    const int t = blockIdx.x;
    int task, i;
    if (t < 672) { task = 0; i = t; }
    else if (t < 1344) { task = 1; i = t - 672; }
    else { task = 2; i = t - 1344; }
    int lvl, j;
    if (i < 512) { lvl = 0; j = i; }
    else if (i < 640) { lvl = 1; j = i - 512; }
    else { lvl = 2; j = i - 640; }
    const int logW = 7 - lvl;
    const int W = 1 << logW, H = W, HW = H * W;
    const float* sou = lvl == 0 ? p.sou0 : (lvl == 1 ? p.sou1 : p.sou2);
    float* ws = p.ws;
    float* OFFM = ws + (lvl == 0 ? 0 : (lvl == 1 ? 2359296 : 2949120));
    float* MOD = ws + (lvl == 0 ? 3096576 : (lvl == 1 ? 4276224 : 4571136));
    const float* WREP = ws + 4730880 + lvl * 62784;
    float* XT = p.out + (lvl == 0 ? 655360 : (lvl == 1 ? 131072 : 0));

    if (task == 0) {  // ---- offset conv: 32ch(concat) -> 18, sigmoid map
        const int nper = 64 >> (2 * lvl);
        const int qb = j % nper, g = (j / nper) & 3, b = j / (nper * 4);
        const int q = qb * 256 + threadIdx.x;
        const int h = q >> logW, x = q & (W - 1);
        const float* ref = lvl == 0 ? p.ref0 : (lvl == 1 ? p.ref1 : p.ref2);
        const float* wt = WREP + 36864;
        const float* bias = lvl == 0 ? p.ob0 : (lvl == 1 ? p.ob1 : p.ob2);
        const float rng = 0.25f * (float)H;
        float acc[18];
#pragma unroll
        for (int u = 0; u < 18; ++u) acc[u] = 0.f;
        const float* base_s = sou + (size_t)(b * 64 + g * 16) * HW;
        const float* base_r = ref + (size_t)(b * 64 + g * 16) * HW;
        for (int ic = 0; ic < 32; ++ic) {
            const float* plane = (ic < 16) ? base_s + (size_t)ic * HW : base_r + (size_t)(ic - 16) * HW;
            const float* wp = wt + ic * 162;
#pragma unroll
            for (int ky = 0; ky < 3; ++ky) {
                int yy = h + ky - 1;
                bool yok = (yy >= 0) && (yy < H);
                const float* row = plane + (size_t)min(max(yy, 0), H - 1) * W;
#pragma unroll
                for (int kx = 0; kx < 3; ++kx) {
                    int xx = x + kx - 1;
                    bool ok = yok && (xx >= 0) && (xx < W);
                    float v = ok ? row[min(max(xx, 0), W - 1)] : 0.f;
                    const float* wk = wp + (ky * 3 + kx) * 18;
#pragma unroll
                    for (int oc = 0; oc < 18; ++oc) acc[oc] = fmaf(v, wk[oc], acc[oc]);
                }
            }
        }
#pragma unroll
        for (int oc = 0; oc < 18; ++oc) {
            float v = acc[oc] + bias[oc];
            OFFM[(size_t)(b * 72 + g * 18 + oc) * HW + q] = rng * (2.f * sigmoidf_(v) - 1.f);
        }
    } else if (task == 1) {  // ---- modulator conv: 64 -> 36, 2*sigmoid, oc split by wave
        const int nper = 256 >> (2 * lvl);
        const int qb = j % nper, b = j / nper;
        const int o0 = __builtin_amdgcn_readfirstlane((int)threadIdx.x >> 6) * 9;
        const int lane = threadIdx.x & 63;
        const int q = qb * 64 + lane;
        const int h = q >> logW, x = q & (W - 1);
        const float* wt = WREP + 42048;
        const float* bias = lvl == 0 ? p.mb0 : (lvl == 1 ? p.mb1 : p.mb2);
        float acc[9];
#pragma unroll
        for (int u = 0; u < 9; ++u) acc[u] = 0.f;
        const float* base = sou + (size_t)b * 64 * HW;
        for (int ic = 0; ic < 64; ++ic) {
            const float* plane = base + (size_t)ic * HW;
            const float* wp = wt + ic * 324 + o0;
#pragma unroll
            for (int ky = 0; ky < 3; ++ky) {
                int yy = h + ky - 1;
                bool yok = (yy >= 0) && (yy < H);
                const float* row = plane + (size_t)min(max(yy, 0), H - 1) * W;
#pragma unroll
                for (int kx = 0; kx < 3; ++kx) {
                    int xx = x + kx - 1;
                    bool ok = yok && (xx >= 0) && (xx < W);
                    float v = ok ? row[min(max(xx, 0), W - 1)] : 0.f;
                    const float* wk = wp + (ky * 3 + kx) * 36;
#pragma unroll
                    for (int oc = 0; oc < 9; ++oc) acc[oc] = fmaf(v, wk[oc], acc[oc]);
                }
            }
        }
#pragma unroll
        for (int oc = 0; oc < 9; ++oc)
            MOD[(size_t)(b * 36 + o0 + oc) * HW + q] = 2.f * sigmoidf_(acc[oc] + bias[o0 + oc]);
    } else {  // ---- transpose (b,64,H,W) -> XT (b,g,HW,16)
        const int nper = 64 >> (2 * lvl);
        const int qb = j % nper, g = (j / nper) & 3, b = j / (nper * 4);
        const int tt = threadIdx.x;
        const int q0 = qb * 256;
        const float* src = sou + (size_t)(b * 64 + g * 16) * HW + q0;
#pragma unroll
        for (int c = 0; c < 16; ++c) tile[tt][c] = src[(size_t)c * HW + tt];
        __syncthreads();
        float4* dst = (float4*)(XT + ((size_t)(b * 4 + g) * HW + q0) * 16);
#pragma unroll
        for (int u = 0; u < 4; ++u) {
            int f4 = u * 256 + tt;
            int q = f4 >> 2, c4 = (f4 & 3) * 4;
            dst[f4] = make_float4(tile[q][c4], tile[q][c4 + 1], tile[q][c4 + 2], tile[q][c4 + 3]);
        }
    }
}

// ---------------- K2: gather(6048) + mean(168) ----------------------------------------
__global__ __launch_bounds__(256) void k2_gather(P p) {
    const int t = blockIdx.x;
    float* ws = p.ws;
    if (t < 6048) {
        int lvl, j;
        if (t < 4608) { lvl = 0; j = t; }
        else if (t < 5760) { lvl = 1; j = t - 4608; }
        else { lvl = 2; j = t - 5760; }
        const int logW = 7 - lvl;
        const int W = 1 << logW, H = W, HW = H * W;
        const int nper = 64 >> (2 * lvl);
        const int qb = j % nper, gk = (j / nper) % 36, b = j / (nper * 36);
        const int g = gk / 9, k = gk - g * 9;
        const float* OFFM = ws + (lvl == 0 ? 0 : (lvl == 1 ? 2359296 : 2949120));
        const float* MOD = ws + (lvl == 0 ? 3096576 : (lvl == 1 ? 4276224 : 4571136));
        const float* XT = p.out + (lvl == 0 ? 655360 : (lvl == 1 ? 131072 : 0));
        unsigned* S = (unsigned*)(ws + 4919232) + (lvl == 0 ? 0 : (lvl == 1 ? 9437184 : 11796480));
        const int q = qb * 256 + threadIdx.x;
        const int h = q >> logW, xp = q & (W - 1);
        const int ky = k / 3, kx = k - ky * 3;
        float dy = OFFM[(size_t)(b * 72 + g * 18 + 2 * k) * HW + q];
        float dx = OFFM[(size_t)(b * 72 + g * 18 + 2 * k + 1) * HW + q];
        float m = MOD[(size_t)(b * 36 + g * 9 + k) * HW + q];
        float py = (float)(h - 1 + ky) + dy;
        float px = (float)(xp - 1 + kx) + dx;
        float y0f = floorf(py), x0f = floorf(px);
        float wy = py - y0f, wx = px - x0f;
        int y0 = (int)y0f, x0 = (int)x0f;
        const float* xg = XT + (size_t)(b * 4 + g) * HW * 16;
        float s[16];
#pragma unroll
        for (int c = 0; c < 16; ++c) s[c] = 0.f;
#pragma unroll
        for (int cor = 0; cor < 4; ++cor) {
            int yy = y0 + (cor >> 1), xx = x0 + (cor & 1);
            float cw = ((cor >> 1) ? wy : 1.f - wy) * ((cor & 1) ? wx : 1.f - wx);
            cw = (yy >= 0 && yy < H && xx >= 0 && xx < W) ? cw * m : 0.f;
            int yc = min(max(yy, 0), H - 1), xc = min(max(xx, 0), W - 1);
            const float4* pp = (const float4*)(xg + (size_t)((yc << logW) + xc) * 16);
            float4 v0 = pp[0], v1 = pp[1], v2 = pp[2], v3 = pp[3];
            s[0] = fmaf(cw, v0.x, s[0]);   s[1] = fmaf(cw, v0.y, s[1]);
            s[2] = fmaf(cw, v0.z, s[2]);   s[3] = fmaf(cw, v0.w, s[3]);
            s[4] = fmaf(cw, v1.x, s[4]);   s[5] = fmaf(cw, v1.y, s[5]);
            s[6] = fmaf(cw, v1.z, s[6]);   s[7] = fmaf(cw, v1.w, s[7]);
            s[8] = fmaf(cw, v2.x, s[8]);   s[9] = fmaf(cw, v2.y, s[9]);
            s[10] = fmaf(cw, v2.z, s[10]); s[11] = fmaf(cw, v2.w, s[11]);
            s[12] = fmaf(cw, v3.x, s[12]); s[13] = fmaf(cw, v3.y, s[13]);
            s[14] = fmaf(cw, v3.z, s[14]); s[15] = fmaf(cw, v3.w, s[15]);
        }
        unsigned* Sp = S + (size_t)(b * 288 + gk * 8) * HW + q;
#pragma unroll
        for (int pr = 0; pr < 8; ++pr) {
            unsigned u = bf16rne(s[2 * pr]) | (bf16rne(s[2 * pr + 1]) << 16);
            Sp[(size_t)pr * HW] = u;
        }
    } else {
        int i = t - 6048;
        int lvl, j;
        if (i < 128) { lvl = 0; j = i; }
        else if (i < 160) { lvl = 1; j = i - 128; }
        else { lvl = 2; j = i - 160; }
        const int HW = 16384 >> (2 * lvl);
        const int nper = 64 >> (2 * lvl);
        const int qb = j % nper, b = j / nper;
        const float* OFFM = ws + (lvl == 0 ? 0 : (lvl == 1 ? 2359296 : 2949120));
        float* MEAN = ws + (lvl == 0 ? 4644864 : (lvl == 1 ? 4710400 : 4726784));
        const int q = qb * 256 + threadIdx.x;
        const float* pp = OFFM + (size_t)b * 72 * HW + q;
        float sy = 0.f, sx = 0.f;
#pragma unroll
        for (int u = 0; u < 36; ++u) {
            sy += pp[(size_t)(2 * u) * HW];
            sx += pp[(size_t)(2 * u + 1) * HW];
        }
        MEAN[(size_t)(b * 2) * HW + q] = sy * (1.f / 36.f);
        MEAN[(size_t)(b * 2 + 1) * HW + q] = sx * (1.f / 36.f);
    }
}

// ---------------- K3: dgemm(672, 2x144-row LDS chunks) + upsample(3072) ---------------
__global__ __launch_bounds__(256, 4) void k3_out(P p) {
    __shared__ unsigned lds[144 * 64];  // 36 KB -> 4 blocks/CU
    const int t = blockIdx.x;
    float* ws = p.ws;
    if (t < 672) {
        int lvl, j;
        if (t < 512) { lvl = 0; j = t; }
        else if (t < 640) { lvl = 1; j = t - 512; }
        else { lvl = 2; j = t - 640; }
        const int HW = 16384 >> (2 * lvl);
        const int nper = 256 >> (2 * lvl);
        const int qb = j % nper, b = j / nper;
        const unsigned* S = (const unsigned*)(ws + 4919232) +
                            (lvl == 0 ? 0 : (lvl == 1 ? 9437184 : 11796480));
        const float* wt = ws + 4730880 + lvl * 62784;
        float* outp = p.out + (lvl == 0 ? 655360 : (lvl == 1 ? 131072 : 0));
        const int q0 = qb * 64;
        const int tid = threadIdx.x;
        const int wvu = __builtin_amdgcn_readfirstlane(tid >> 6);
        const int lane = tid & 63;
        float acc[16];
#pragma unroll
        for (int o = 0; o < 16; ++o) acc[o] = 0.f;
        for (int chk = 0; chk < 2; ++chk) {
            __syncthreads();
            const unsigned* Sb = S + (size_t)(b * 288 + chk * 144) * HW + q0;
            for (int i = tid; i < 144 * 16; i += 256) {
                int r = i >> 4, ch = (i & 15) << 2;
                *(uint4*)&lds[r * 64 + ch] = *(const uint4*)(Sb + (size_t)r * HW + ch);
            }
            __syncthreads();
            const float* wbase = wt + chk * 144 * 128 + wvu * 16;
#pragma unroll 2
            for (int r = 0; r < 144; ++r) {
                unsigned u = lds[r * 64 + lane];
                float flo = __uint_as_float(u << 16);
                float fhi = __uint_as_float(u & 0xFFFF0000u);
                const float* wp = wbase + r * 128;
#pragma unroll
                for (int o = 0; o < 16; ++o) acc[o] = fmaf(flo, wp[o], acc[o]);
#pragma unroll
                for (int o = 0; o < 16; ++o) acc[o] = fmaf(fhi, wp[64 + o], acc[o]);
            }
        }
        float* op = outp + (size_t)(b * 64 + wvu * 16) * HW + q0 + lane;
#pragma unroll
        for (int o = 0; o < 16; ++o) op[(size_t)o * HW] = acc[o];
    } else {
        // upsample: 4 px/thread over flat [lvl][b][c][512][512]
        int i = t - 672;  // 0..3071
        int flat = (i * 256 + (int)threadIdx.x) * 4;
        int lvl = flat >> 20;
        int r = flat & 1048575;
        int b = r >> 19, c = (r >> 18) & 1;
        int pix = r & 262143;
        int yo = pix >> 9, xo = pix & 511;
        const int H = 128 >> lvl, W = H;
        const float* MEAN = ws + (lvl == 0 ? 4644864 : (lvl == 1 ? 4710400 : 4726784));
        const float* m = MEAN + (size_t)(b * 2 + c) * H * W;
        float* o = p.out + (lvl == 0 ? 4849664 : (lvl == 1 ? 3801088 : 2752512)) +
                   ((size_t)(b * 2 + c) * 512 + yo) * 512 + xo;
        const float fs = (float)(4 << lvl);
        const float sc = (float)(H - 1) * (1.f / 511.f);
        float sy = yo * sc;
        int y0 = min((int)sy, H - 2);
        float wy = sy - (float)y0;
        float rr[4];
#pragma unroll
        for (int u = 0; u < 4; ++u) {
            float sx = (float)(xo + u) * sc;
            int x0 = min((int)sx, W - 2);
            float wx = sx - (float)x0;
            float v00 = m[y0 * W + x0], v01 = m[y0 * W + x0 + 1];
            float v10 = m[(y0 + 1) * W + x0], v11 = m[(y0 + 1) * W + x0 + 1];
            float r0 = v00 * (1.f - wy) + v10 * wy;
            float r1 = v01 * (1.f - wy) + v11 * wy;
            rr[u] = (r0 * (1.f - wx) + r1 * wx) * fs;
        }
        *(float4*)o = make_float4(rr[0], rr[1], rr[2], rr[3]);
    }
}

extern "C" void kernel_launch(void* const* d_in, const int* in_sizes, int n_in,
                              void* d_out, int out_size, void* d_ws, size_t ws_size,
                              hipStream_t stream) {
    const float* fin[21];
    for (int i = 0; i < 21; ++i) fin[i] = (const float*)d_in[i];
    P p;
    if (in_sizes[1] == in_sizes[0]) {  // dict order sou1,ref1,sou2,ref2,sou3,ref3
        p.sou0 = fin[0]; p.ref0 = fin[1];
        p.sou1 = fin[2]; p.ref1 = fin[3];
        p.sou2 = fin[4]; p.ref2 = fin[5];
    } else {  // arg order
        p.sou0 = fin[0]; p.sou1 = fin[1]; p.sou2 = fin[2];
        p.ref0 = fin[3]; p.ref1 = fin[4]; p.ref2 = fin[5];
    }
    p.ob0 = fin[7]; p.mb0 = fin[9];
    p.ob1 = fin[12]; p.mb1 = fin[14];
    p.ob2 = fin[17]; p.mb2 = fin[19];
    p.out = (float*)d_out;
    p.ws = (float*)d_ws;

    repack_all<<<dim3(144, 3), 256, 0, stream>>>(
        fin[6], fin[8], fin[10], fin[11], fin[13], fin[15], fin[16], fin[18], fin[20],
        p.ws + 4730880);
    k1_prep<<<dim3(2016), 256, 0, stream>>>(p);
    k2_gather<<<dim3(6216), 256, 0, stream>>>(p);
    k3_out<<<dim3(3744), 256, 0, stream>>>(p);
}

// Round 7
// 618.123 us; speedup vs baseline: 2.4073x; 1.5056x over previous
//
#include <hip/hip_runtime.h>

__device__ __forceinline__ float sigmoidf_(float x) { return 1.f / (1.f + __expf(-x)); }
__device__ __forceinline__ unsigned bf16rne(float x) {
    unsigned b = __float_as_uint(x);
    return (b + 0x7FFFu + ((b >> 16) & 1u)) >> 16;
}

// ws layout (float words):
//   OFFM:  lvl0 @0 (2359296), lvl1 @2359296 (589824), lvl2 @2949120 (147456)
//   MOD:   lvl0 @3096576 (1179648), lvl1 @4276224 (294912), lvl2 @4571136 (73728)
//   MEAN:  lvl0 @4644864 (65536), lvl1 @4710400 (16384), lvl2 @4726784 (4096)
//   WREP:  @4730880, 3*62784 (per lvl: [36864 reg][5184 off][20736 mod])
//   S:     @4919232 (uints), lvl0 +0 (9437184), lvl1 +9437184 (2359296), lvl2 +11796480 (589824)
// XT lives in d_out's feat region (consumed in K2, overwritten in K3):
//   lvl0 @out+655360, lvl1 @out+131072, lvl2 @out+0

struct P {
    const float *sou0, *sou1, *sou2;
    const float *ref0, *ref1, *ref2;
    const float *ob0, *ob1, *ob2;
    const float *mb0, *mb1, *mb2;
    float* out;
    float* ws;
};

// ---------------- K0: fused weight repack (all levels) --------------------------------
__global__ __launch_bounds__(256) void repack_all(
    const float* __restrict__ ow0, const float* __restrict__ mw0, const float* __restrict__ rw0,
    const float* __restrict__ ow1, const float* __restrict__ mw1, const float* __restrict__ rw1,
    const float* __restrict__ ow2, const float* __restrict__ mw2, const float* __restrict__ rw2,
    float* __restrict__ dst) {
    const int lvl = blockIdx.y;
    const float* ow = lvl == 0 ? ow0 : (lvl == 1 ? ow1 : ow2);
    const float* mw = lvl == 0 ? mw0 : (lvl == 1 ? mw1 : mw2);
    const float* rw = lvl == 0 ? rw0 : (lvl == 1 ? rw1 : rw2);
    float* d = dst + lvl * 62784;
    int i = blockIdx.x * 256 + threadIdx.x;
    if (i < 36864) {  // reg -> [g][k][c16][o64]
        int o = i % 64, c = (i / 64) % 16, k = (i / 1024) % 9, g = i / 9216;
        d[i] = rw[o * 576 + (g * 16 + c) * 9 + k];
    }
    if (i < 5184) {   // off -> [ic][k][18]
        int oc = i % 18, k = (i / 18) % 9, ic = i / 162;
        d[36864 + i] = ow[oc * 288 + ic * 9 + k];
    }
    if (i < 20736) {  // mod -> [ic][k][36]
        int oc = i % 36, k = (i / 36) % 9, ic = i / 324;
        d[42048 + i] = mw[oc * 576 + ic * 9 + k];
    }
}

// ---------------- K1: offset_conv(672) + mod_conv(672) + transpose(672) ---------------
// NO launch_bounds beyond max-threads, NO unroll. History: unroll2 -> 188 VGPR, 2 blk/CU
// (R4, 290us); bound=6 -> 40 VGPR SPILL 4.7GB (R5); bound=4 -> 64 VGPR SPILL 1.9GB (R6).
// Empirically bound w caps VGPR at ~256/w on this toolchain. Unbounded allocator never
// spills; grid is 7.9 blocks/CU so residency is allocation-limited (~4-8 blk/CU).
__global__ __launch_bounds__(256) void k1_prep(P p) {
    __shared__ float tile[256][17];
    const int t = blockIdx.x;
    int task, i;
    if (t < 672) { task = 0; i = t; }
    else if (t < 1344) { task = 1; i = t - 672; }
    else { task = 2; i = t - 1344; }
    int lvl, j;
    if (i < 512) { lvl = 0; j = i; }
    else if (i < 640) { lvl = 1; j = i - 512; }
    else { lvl = 2; j = i - 640; }
    const int logW = 7 - lvl;
    const int W = 1 << logW, H = W, HW = H * W;
    const float* sou = lvl == 0 ? p.sou0 : (lvl == 1 ? p.sou1 : p.sou2);
    float* ws = p.ws;
    float* OFFM = ws + (lvl == 0 ? 0 : (lvl == 1 ? 2359296 : 2949120));
    float* MOD = ws + (lvl == 0 ? 3096576 : (lvl == 1 ? 4276224 : 4571136));
    const float* WREP = ws + 4730880 + lvl * 62784;
    float* XT = p.out + (lvl == 0 ? 655360 : (lvl == 1 ? 131072 : 0));

    if (task == 0) {  // ---- offset conv: 32ch(concat) -> 18, sigmoid map
        const int nper = 64 >> (2 * lvl);
        const int qb = j % nper, g = (j / nper) & 3, b = j / (nper * 4);
        const int q = qb * 256 + threadIdx.x;
        const int h = q >> logW, x = q & (W - 1);
        const float* ref = lvl == 0 ? p.ref0 : (lvl == 1 ? p.ref1 : p.ref2);
        const float* wt = WREP + 36864;
        const float* bias = lvl == 0 ? p.ob0 : (lvl == 1 ? p.ob1 : p.ob2);
        const float rng = 0.25f * (float)H;
        float acc[18];
#pragma unroll
        for (int u = 0; u < 18; ++u) acc[u] = 0.f;
        const float* base_s = sou + (size_t)(b * 64 + g * 16) * HW;
        const float* base_r = ref + (size_t)(b * 64 + g * 16) * HW;
        for (int ic = 0; ic < 32; ++ic) {
            const float* plane = (ic < 16) ? base_s + (size_t)ic * HW : base_r + (size_t)(ic - 16) * HW;
            const float* wp = wt + ic * 162;
#pragma unroll
            for (int ky = 0; ky < 3; ++ky) {
                int yy = h + ky - 1;
                bool yok = (yy >= 0) && (yy < H);
                const float* row = plane + (size_t)min(max(yy, 0), H - 1) * W;
#pragma unroll
                for (int kx = 0; kx < 3; ++kx) {
                    int xx = x + kx - 1;
                    bool ok = yok && (xx >= 0) && (xx < W);
                    float v = ok ? row[min(max(xx, 0), W - 1)] : 0.f;
                    const float* wk = wp + (ky * 3 + kx) * 18;
#pragma unroll
                    for (int oc = 0; oc < 18; ++oc) acc[oc] = fmaf(v, wk[oc], acc[oc]);
                }
            }
        }
#pragma unroll
        for (int oc = 0; oc < 18; ++oc) {
            float v = acc[oc] + bias[oc];
            OFFM[(size_t)(b * 72 + g * 18 + oc) * HW + q] = rng * (2.f * sigmoidf_(v) - 1.f);
        }
    } else if (task == 1) {  // ---- modulator conv: 64 -> 36, 2*sigmoid, oc split by wave
        const int nper = 256 >> (2 * lvl);
        const int qb = j % nper, b = j / nper;
        const int o0 = __builtin_amdgcn_readfirstlane((int)threadIdx.x >> 6) * 9;
        const int lane = threadIdx.x & 63;
        const int q = qb * 64 + lane;
        const int h = q >> logW, x = q & (W - 1);
        const float* wt = WREP + 42048;
        const float* bias = lvl == 0 ? p.mb0 : (lvl == 1 ? p.mb1 : p.mb2);
        float acc[9];
#pragma unroll
        for (int u = 0; u < 9; ++u) acc[u] = 0.f;
        const float* base = sou + (size_t)b * 64 * HW;
        for (int ic = 0; ic < 64; ++ic) {
            const float* plane = base + (size_t)ic * HW;
            const float* wp = wt + ic * 324 + o0;
#pragma unroll
            for (int ky = 0; ky < 3; ++ky) {
                int yy = h + ky - 1;
                bool yok = (yy >= 0) && (yy < H);
                const float* row = plane + (size_t)min(max(yy, 0), H - 1) * W;
#pragma unroll
                for (int kx = 0; kx < 3; ++kx) {
                    int xx = x + kx - 1;
                    bool ok = yok && (xx >= 0) && (xx < W);
                    float v = ok ? row[min(max(xx, 0), W - 1)] : 0.f;
                    const float* wk = wp + (ky * 3 + kx) * 36;
#pragma unroll
                    for (int oc = 0; oc < 9; ++oc) acc[oc] = fmaf(v, wk[oc], acc[oc]);
                }
            }
        }
#pragma unroll
        for (int oc = 0; oc < 9; ++oc)
            MOD[(size_t)(b * 36 + o0 + oc) * HW + q] = 2.f * sigmoidf_(acc[oc] + bias[o0 + oc]);
    } else {  // ---- transpose (b,64,H,W) -> XT (b,g,HW,16)
        const int nper = 64 >> (2 * lvl);
        const int qb = j % nper, g = (j / nper) & 3, b = j / (nper * 4);
        const int tt = threadIdx.x;
        const int q0 = qb * 256;
        const float* src = sou + (size_t)(b * 64 + g * 16) * HW + q0;
#pragma unroll
        for (int c = 0; c < 16; ++c) tile[tt][c] = src[(size_t)c * HW + tt];
        __syncthreads();
        float4* dst = (float4*)(XT + ((size_t)(b * 4 + g) * HW + q0) * 16);
#pragma unroll
        for (int u = 0; u < 4; ++u) {
            int f4 = u * 256 + tt;
            int q = f4 >> 2, c4 = (f4 & 3) * 4;
            dst[f4] = make_float4(tile[q][c4], tile[q][c4 + 1], tile[q][c4 + 2], tile[q][c4 + 3]);
        }
    }
}

// ---------------- K2: gather(6048) + mean(168) ----------------------------------------
__global__ __launch_bounds__(256) void k2_gather(P p) {
    const int t = blockIdx.x;
    float* ws = p.ws;
    if (t < 6048) {
        int lvl, j;
        if (t < 4608) { lvl = 0; j = t; }
        else if (t < 5760) { lvl = 1; j = t - 4608; }
        else { lvl = 2; j = t - 5760; }
        const int logW = 7 - lvl;
        const int W = 1 << logW, H = W, HW = H * W;
        const int nper = 64 >> (2 * lvl);
        const int qb = j % nper, gk = (j / nper) % 36, b = j / (nper * 36);
        const int g = gk / 9, k = gk - g * 9;
        const float* OFFM = ws + (lvl == 0 ? 0 : (lvl == 1 ? 2359296 : 2949120));
        const float* MOD = ws + (lvl == 0 ? 3096576 : (lvl == 1 ? 4276224 : 4571136));
        const float* XT = p.out + (lvl == 0 ? 655360 : (lvl == 1 ? 131072 : 0));
        unsigned* S = (unsigned*)(ws + 4919232) + (lvl == 0 ? 0 : (lvl == 1 ? 9437184 : 11796480));
        const int q = qb * 256 + threadIdx.x;
        const int h = q >> logW, xp = q & (W - 1);
        const int ky = k / 3, kx = k - ky * 3;
        float dy = OFFM[(size_t)(b * 72 + g * 18 + 2 * k) * HW + q];
        float dx = OFFM[(size_t)(b * 72 + g * 18 + 2 * k + 1) * HW + q];
        float m = MOD[(size_t)(b * 36 + g * 9 + k) * HW + q];
        float py = (float)(h - 1 + ky) + dy;
        float px = (float)(xp - 1 + kx) + dx;
        float y0f = floorf(py), x0f = floorf(px);
        float wy = py - y0f, wx = px - x0f;
        int y0 = (int)y0f, x0 = (int)x0f;
        const float* xg = XT + (size_t)(b * 4 + g) * HW * 16;
        float s[16];
#pragma unroll
        for (int c = 0; c < 16; ++c) s[c] = 0.f;
#pragma unroll
        for (int cor = 0; cor < 4; ++cor) {
            int yy = y0 + (cor >> 1), xx = x0 + (cor & 1);
            float cw = ((cor >> 1) ? wy : 1.f - wy) * ((cor & 1) ? wx : 1.f - wx);
            cw = (yy >= 0 && yy < H && xx >= 0 && xx < W) ? cw * m : 0.f;
            int yc = min(max(yy, 0), H - 1), xc = min(max(xx, 0), W - 1);
            const float4* pp = (const float4*)(xg + (size_t)((yc << logW) + xc) * 16);
            float4 v0 = pp[0], v1 = pp[1], v2 = pp[2], v3 = pp[3];
            s[0] = fmaf(cw, v0.x, s[0]);   s[1] = fmaf(cw, v0.y, s[1]);
            s[2] = fmaf(cw, v0.z, s[2]);   s[3] = fmaf(cw, v0.w, s[3]);
            s[4] = fmaf(cw, v1.x, s[4]);   s[5] = fmaf(cw, v1.y, s[5]);
            s[6] = fmaf(cw, v1.z, s[6]);   s[7] = fmaf(cw, v1.w, s[7]);
            s[8] = fmaf(cw, v2.x, s[8]);   s[9] = fmaf(cw, v2.y, s[9]);
            s[10] = fmaf(cw, v2.z, s[10]); s[11] = fmaf(cw, v2.w, s[11]);
            s[12] = fmaf(cw, v3.x, s[12]); s[13] = fmaf(cw, v3.y, s[13]);
            s[14] = fmaf(cw, v3.z, s[14]); s[15] = fmaf(cw, v3.w, s[15]);
        }
        unsigned* Sp = S + (size_t)(b * 288 + gk * 8) * HW + q;
#pragma unroll
        for (int pr = 0; pr < 8; ++pr) {
            unsigned u = bf16rne(s[2 * pr]) | (bf16rne(s[2 * pr + 1]) << 16);
            Sp[(size_t)pr * HW] = u;
        }
    } else {
        int i = t - 6048;
        int lvl, j;
        if (i < 128) { lvl = 0; j = i; }
        else if (i < 160) { lvl = 1; j = i - 128; }
        else { lvl = 2; j = i - 160; }
        const int HW = 16384 >> (2 * lvl);
        const int nper = 64 >> (2 * lvl);
        const int qb = j % nper, b = j / nper;
        const float* OFFM = ws + (lvl == 0 ? 0 : (lvl == 1 ? 2359296 : 2949120));
        float* MEAN = ws + (lvl == 0 ? 4644864 : (lvl == 1 ? 4710400 : 4726784));
        const int q = qb * 256 + threadIdx.x;
        const float* pp = OFFM + (size_t)b * 72 * HW + q;
        float sy = 0.f, sx = 0.f;
#pragma unroll
        for (int u = 0; u < 36; ++u) {
            sy += pp[(size_t)(2 * u) * HW];
            sx += pp[(size_t)(2 * u + 1) * HW];
        }
        MEAN[(size_t)(b * 2) * HW + q] = sy * (1.f / 36.f);
        MEAN[(size_t)(b * 2 + 1) * HW + q] = sx * (1.f / 36.f);
    }
}

// ---------------- K3: dgemm(672, 2x144-row LDS chunks) + upsample(3072) ---------------
// No waves bound: 36 KB LDS already caps at 4 blocks/CU; a VGPR bound only risks spill
// (dgemm body needs ~88 VGPR standalone, R2).
__global__ __launch_bounds__(256) void k3_out(P p) {
    __shared__ unsigned lds[144 * 64];  // 36 KB -> 4 blocks/CU
    const int t = blockIdx.x;
    float* ws = p.ws;
    if (t < 672) {
        int lvl, j;
        if (t < 512) { lvl = 0; j = t; }
        else if (t < 640) { lvl = 1; j = t - 512; }
        else { lvl = 2; j = t - 640; }
        const int HW = 16384 >> (2 * lvl);
        const int nper = 256 >> (2 * lvl);
        const int qb = j % nper, b = j / nper;
        const unsigned* S = (const unsigned*)(ws + 4919232) +
                            (lvl == 0 ? 0 : (lvl == 1 ? 9437184 : 11796480));
        const float* wt = ws + 4730880 + lvl * 62784;
        float* outp = p.out + (lvl == 0 ? 655360 : (lvl == 1 ? 131072 : 0));
        const int q0 = qb * 64;
        const int tid = threadIdx.x;
        const int wvu = __builtin_amdgcn_readfirstlane(tid >> 6);
        const int lane = tid & 63;
        float acc[16];
#pragma unroll
        for (int o = 0; o < 16; ++o) acc[o] = 0.f;
        for (int chk = 0; chk < 2; ++chk) {
            __syncthreads();
            const unsigned* Sb = S + (size_t)(b * 288 + chk * 144) * HW + q0;
            for (int i = tid; i < 144 * 16; i += 256) {
                int r = i >> 4, ch = (i & 15) << 2;
                *(uint4*)&lds[r * 64 + ch] = *(const uint4*)(Sb + (size_t)r * HW + ch);
            }
            __syncthreads();
            const float* wbase = wt + chk * 144 * 128 + wvu * 16;
#pragma unroll 2
            for (int r = 0; r < 144; ++r) {
                unsigned u = lds[r * 64 + lane];
                float flo = __uint_as_float(u << 16);
                float fhi = __uint_as_float(u & 0xFFFF0000u);
                const float* wp = wbase + r * 128;
#pragma unroll
                for (int o = 0; o < 16; ++o) acc[o] = fmaf(flo, wp[o], acc[o]);
#pragma unroll
                for (int o = 0; o < 16; ++o) acc[o] = fmaf(fhi, wp[64 + o], acc[o]);
            }
        }
        float* op = outp + (size_t)(b * 64 + wvu * 16) * HW + q0 + lane;
#pragma unroll
        for (int o = 0; o < 16; ++o) op[(size_t)o * HW] = acc[o];
    } else {
        // upsample: 4 px/thread over flat [lvl][b][c][512][512]
        int i = t - 672;  // 0..3071
        int flat = (i * 256 + (int)threadIdx.x) * 4;
        int lvl = flat >> 20;
        int r = flat & 1048575;
        int b = r >> 19, c = (r >> 18) & 1;
        int pix = r & 262143;
        int yo = pix >> 9, xo = pix & 511;
        const int H = 128 >> lvl, W = H;
        const float* MEAN = ws + (lvl == 0 ? 4644864 : (lvl == 1 ? 4710400 : 4726784));
        const float* m = MEAN + (size_t)(b * 2 + c) * H * W;
        float* o = p.out + (lvl == 0 ? 4849664 : (lvl == 1 ? 3801088 : 2752512)) +
                   ((size_t)(b * 2 + c) * 512 + yo) * 512 + xo;
        const float fs = (float)(4 << lvl);
        const float sc = (float)(H - 1) * (1.f / 511.f);
        float sy = yo * sc;
        int y0 = min((int)sy, H - 2);
        float wy = sy - (float)y0;
        float rr[4];
#pragma unroll
        for (int u = 0; u < 4; ++u) {
            float sx = (float)(xo + u) * sc;
            int x0 = min((int)sx, W - 2);
            float wx = sx - (float)x0;
            float v00 = m[y0 * W + x0], v01 = m[y0 * W + x0 + 1];
            float v10 = m[(y0 + 1) * W + x0], v11 = m[(y0 + 1) * W + x0 + 1];
            float r0 = v00 * (1.f - wy) + v10 * wy;
            float r1 = v01 * (1.f - wy) + v11 * wy;
            rr[u] = (r0 * (1.f - wx) + r1 * wx) * fs;
        }
        *(float4*)o = make_float4(rr[0], rr[1], rr[2], rr[3]);
    }
}

extern "C" void kernel_launch(void* const* d_in, const int* in_sizes, int n_in,
                              void* d_out, int out_size, void* d_ws, size_t ws_size,
                              hipStream_t stream) {
    const float* fin[21];
    for (int i = 0; i < 21; ++i) fin[i] = (const float*)d_in[i];
    P p;
    if (in_sizes[1] == in_sizes[0]) {  // dict order sou1,ref1,sou2,ref2,sou3,ref3
        p.sou0 = fin[0]; p.ref0 = fin[1];
        p.sou1 = fin[2]; p.ref1 = fin[3];
        p.sou2 = fin[4]; p.ref2 = fin[5];
    } else {  // arg order
        p.sou0 = fin[0]; p.sou1 = fin[1]; p.sou2 = fin[2];
        p.ref0 = fin[3]; p.ref1 = fin[4]; p.ref2 = fin[5];
    }
    p.ob0 = fin[7]; p.mb0 = fin[9];
    p.ob1 = fin[12]; p.mb1 = fin[14];
    p.ob2 = fin[17]; p.mb2 = fin[19];
    p.out = (float*)d_out;
    p.ws = (float*)d_ws;

    repack_all<<<dim3(144, 3), 256, 0, stream>>>(
        fin[6], fin[8], fin[10], fin[11], fin[13], fin[15], fin[16], fin[18], fin[20],
        p.ws + 4730880);
    k1_prep<<<dim3(2016), 256, 0, stream>>>(p);
    k2_gather<<<dim3(6216), 256, 0, stream>>>(p);
    k3_out<<<dim3(3744), 256, 0, stream>>>(p);
}

// Round 8
// 497.105 us; speedup vs baseline: 2.9934x; 1.2434x over previous
//
#include <hip/hip_runtime.h>

__device__ __forceinline__ float sigmoidf_(float x) { return 1.f / (1.f + __expf(-x)); }
__device__ __forceinline__ unsigned bf16rne(float x) {
    unsigned b = __float_as_uint(x);
    return (b + 0x7FFFu + ((b >> 16) & 1u)) >> 16;
}

// ws layout (float words):
//   OFFM:  lvl0 @0 (2359296), lvl1 @2359296 (589824), lvl2 @2949120 (147456)
//   MOD:   lvl0 @3096576 (1179648), lvl1 @4276224 (294912), lvl2 @4571136 (73728)
//   MEAN:  lvl0 @4644864 (65536), lvl1 @4710400 (16384), lvl2 @4726784 (4096)
//   WREP:  @4730880, 3*62784 (per lvl: [36864 reg][5184 off][20736 mod])
//   S:     @4919232 (uints), lvl0 +0, lvl1 +9437184, lvl2 +11796480
// XT lives in d_out's feat region (consumed in K2, overwritten in K3):
//   lvl0 @out+655360, lvl1 @out+131072, lvl2 @out+0

struct P {
    const float *sou0, *sou1, *sou2;
    const float *ref0, *ref1, *ref2;
    const float *ob0, *ob1, *ob2;
    const float *mb0, *mb1, *mb2;
    float* out;
    float* ws;
};

// ---------------- K0: fused weight repack (all levels) --------------------------------
__global__ __launch_bounds__(256) void repack_all(
    const float* __restrict__ ow0, const float* __restrict__ mw0, const float* __restrict__ rw0,
    const float* __restrict__ ow1, const float* __restrict__ mw1, const float* __restrict__ rw1,
    const float* __restrict__ ow2, const float* __restrict__ mw2, const float* __restrict__ rw2,
    float* __restrict__ dst) {
    const int lvl = blockIdx.y;
    const float* ow = lvl == 0 ? ow0 : (lvl == 1 ? ow1 : ow2);
    const float* mw = lvl == 0 ? mw0 : (lvl == 1 ? mw1 : mw2);
    const float* rw = lvl == 0 ? rw0 : (lvl == 1 ? rw1 : rw2);
    float* d = dst + lvl * 62784;
    int i = blockIdx.x * 256 + threadIdx.x;
    if (i < 36864) {  // reg -> [g][k][c16][o64]
        int o = i % 64, c = (i / 64) % 16, k = (i / 1024) % 9, g = i / 9216;
        d[i] = rw[o * 576 + (g * 16 + c) * 9 + k];
    }
    if (i < 5184) {   // off -> [ic][k][18]
        int oc = i % 18, k = (i / 18) % 9, ic = i / 162;
        d[36864 + i] = ow[oc * 288 + ic * 9 + k];
    }
    if (i < 20736) {  // mod -> [ic][k][36]
        int oc = i % 36, k = (i / 36) % 9, ic = i / 324;
        d[42048 + i] = mw[oc * 576 + ic * 9 + k];
    }
}

// ---------------- K1: offset_conv(168) + mod_conv(168) + transpose(672) ---------------
// 4 pixels/thread: per (ic,ky) one aligned float4 + 2 edge scalars feed 216 FMAs
// (vs R7's 1 scalar load per 36 FMAs -> 90% stall at VALUBusy 13%).
// No launch_bounds: R5/R6 showed bound w caps VGPR ~256/w and spills (4.7/1.9 GB).
__global__ __launch_bounds__(256) void k1_prep(P p) {
    __shared__ float tile[256][17];
    const int t = blockIdx.x;
    int task, i;
    if (t < 168) { task = 0; i = t; }
    else if (t < 336) { task = 1; i = t - 168; }
    else { task = 2; i = t - 336; }
    float* ws = p.ws;

    if (task == 0) {  // ---- offset conv: 32ch(concat) -> 18, sigmoid map, 4 px/thread
        int lvl, j;
        if (i < 128) { lvl = 0; j = i; }
        else if (i < 160) { lvl = 1; j = i - 128; }
        else { lvl = 2; j = i - 160; }
        const int logW = 7 - lvl;
        const int W = 1 << logW, H = W, HW = H * W;
        const int nper = 16 >> (2 * lvl);
        const int qb = j % nper, g = (j / nper) & 3, b = j / (nper * 4);
        const int q = qb * 1024 + (int)threadIdx.x * 4;
        const int h = q >> logW, x0 = q & (W - 1);
        const float* sou = lvl == 0 ? p.sou0 : (lvl == 1 ? p.sou1 : p.sou2);
        const float* ref = lvl == 0 ? p.ref0 : (lvl == 1 ? p.ref1 : p.ref2);
        const float* wt = ws + 4730880 + lvl * 62784 + 36864;
        const float* bias = lvl == 0 ? p.ob0 : (lvl == 1 ? p.ob1 : p.ob2);
        float* OFFM = ws + (lvl == 0 ? 0 : (lvl == 1 ? 2359296 : 2949120));
        const float rng = 0.25f * (float)H;
        float acc[4][18];
#pragma unroll
        for (int px = 0; px < 4; ++px)
#pragma unroll
            for (int u = 0; u < 18; ++u) acc[px][u] = 0.f;
        const float* base_s = sou + (size_t)(b * 64 + g * 16) * HW;
        const float* base_r = ref + (size_t)(b * 64 + g * 16) * HW;
        for (int ic = 0; ic < 32; ++ic) {
            const float* plane = (ic < 16) ? base_s + (size_t)ic * HW
                                           : base_r + (size_t)(ic - 16) * HW;
            const float* wp = wt + ic * 162;
#pragma unroll
            for (int ky = 0; ky < 3; ++ky) {
                int yy = h + ky - 1;
                bool yok = (yy >= 0) && (yy < H);
                const float* row = plane + (size_t)min(max(yy, 0), H - 1) * W;
                float w[6];
                float4 f4 = yok ? *(const float4*)(row + x0) : make_float4(0.f, 0.f, 0.f, 0.f);
                w[0] = (yok && x0 > 0) ? row[x0 - 1] : 0.f;
                w[1] = f4.x; w[2] = f4.y; w[3] = f4.z; w[4] = f4.w;
                w[5] = (yok && x0 + 4 < W) ? row[x0 + 4] : 0.f;
#pragma unroll
                for (int kx = 0; kx < 3; ++kx) {
                    const float* wk = wp + (ky * 3 + kx) * 18;
#pragma unroll
                    for (int oc = 0; oc < 18; ++oc) {
                        float wv = wk[oc];
#pragma unroll
                        for (int px = 0; px < 4; ++px)
                            acc[px][oc] = fmaf(w[px + kx], wv, acc[px][oc]);
                    }
                }
            }
        }
#pragma unroll
        for (int oc = 0; oc < 18; ++oc) {
            float r[4];
#pragma unroll
            for (int px = 0; px < 4; ++px) {
                float v = acc[px][oc] + bias[oc];
                r[px] = rng * (2.f * sigmoidf_(v) - 1.f);
            }
            *(float4*)&OFFM[(size_t)(b * 72 + g * 18 + oc) * HW + q] =
                make_float4(r[0], r[1], r[2], r[3]);
        }
    } else if (task == 1) {  // ---- modulator conv: 64 -> 36, wave oc-split, 4 px/lane
        int lvl, j;
        if (i < 128) { lvl = 0; j = i; }
        else if (i < 160) { lvl = 1; j = i - 128; }
        else { lvl = 2; j = i - 160; }
        const int logW = 7 - lvl;
        const int W = 1 << logW, H = W, HW = H * W;
        const int nper = 64 >> (2 * lvl);
        const int qb = j % nper, b = j / nper;
        const int o0 = __builtin_amdgcn_readfirstlane((int)threadIdx.x >> 6) * 9;
        const int lane = threadIdx.x & 63;
        const int q = qb * 256 + lane * 4;
        const int h = q >> logW, x0 = q & (W - 1);
        const float* sou = lvl == 0 ? p.sou0 : (lvl == 1 ? p.sou1 : p.sou2);
        const float* wt = ws + 4730880 + lvl * 62784 + 42048;
        const float* bias = lvl == 0 ? p.mb0 : (lvl == 1 ? p.mb1 : p.mb2);
        float* MOD = ws + (lvl == 0 ? 3096576 : (lvl == 1 ? 4276224 : 4571136));
        float acc[4][9];
#pragma unroll
        for (int px = 0; px < 4; ++px)
#pragma unroll
            for (int u = 0; u < 9; ++u) acc[px][u] = 0.f;
        const float* base = sou + (size_t)b * 64 * HW;
        for (int ic = 0; ic < 64; ++ic) {
            const float* plane = base + (size_t)ic * HW;
            const float* wp = wt + ic * 324 + o0;
#pragma unroll
            for (int ky = 0; ky < 3; ++ky) {
                int yy = h + ky - 1;
                bool yok = (yy >= 0) && (yy < H);
                const float* row = plane + (size_t)min(max(yy, 0), H - 1) * W;
                float w[6];
                float4 f4 = yok ? *(const float4*)(row + x0) : make_float4(0.f, 0.f, 0.f, 0.f);
                w[0] = (yok && x0 > 0) ? row[x0 - 1] : 0.f;
                w[1] = f4.x; w[2] = f4.y; w[3] = f4.z; w[4] = f4.w;
                w[5] = (yok && x0 + 4 < W) ? row[x0 + 4] : 0.f;
#pragma unroll
                for (int kx = 0; kx < 3; ++kx) {
                    const float* wk = wp + (ky * 3 + kx) * 36;
#pragma unroll
                    for (int oc = 0; oc < 9; ++oc) {
                        float wv = wk[oc];
#pragma unroll
                        for (int px = 0; px < 4; ++px)
                            acc[px][oc] = fmaf(w[px + kx], wv, acc[px][oc]);
                    }
                }
            }
        }
#pragma unroll
        for (int oc = 0; oc < 9; ++oc) {
            float r[4];
#pragma unroll
            for (int px = 0; px < 4; ++px)
                r[px] = 2.f * sigmoidf_(acc[px][oc] + bias[o0 + oc]);
            *(float4*)&MOD[(size_t)(b * 36 + o0 + oc) * HW + q] =
                make_float4(r[0], r[1], r[2], r[3]);
        }
    } else {  // ---- transpose (b,64,H,W) -> XT (b,g,HW,16)
        int lvl, j;
        if (i < 512) { lvl = 0; j = i; }
        else if (i < 640) { lvl = 1; j = i - 512; }
        else { lvl = 2; j = i - 640; }
        const int HW = 16384 >> (2 * lvl);
        const int nper = 64 >> (2 * lvl);
        const int qb = j % nper, g = (j / nper) & 3, b = j / (nper * 4);
        const float* sou = lvl == 0 ? p.sou0 : (lvl == 1 ? p.sou1 : p.sou2);
        float* XT = p.out + (lvl == 0 ? 655360 : (lvl == 1 ? 131072 : 0));
        const int tt = threadIdx.x;
        const int q0 = qb * 256;
        const float* src = sou + (size_t)(b * 64 + g * 16) * HW + q0;
#pragma unroll
        for (int c = 0; c < 16; ++c) tile[tt][c] = src[(size_t)c * HW + tt];
        __syncthreads();
        float4* dst = (float4*)(XT + ((size_t)(b * 4 + g) * HW + q0) * 16);
#pragma unroll
        for (int u = 0; u < 4; ++u) {
            int f4 = u * 256 + tt;
            int q = f4 >> 2, c4 = (f4 & 3) * 4;
            dst[f4] = make_float4(tile[q][c4], tile[q][c4 + 1], tile[q][c4 + 2], tile[q][c4 + 3]);
        }
    }
}

// ---------------- K2: gather(6048) + mean(168) ----------------------------------------
__global__ __launch_bounds__(256) void k2_gather(P p) {
    const int t = blockIdx.x;
    float* ws = p.ws;
    if (t < 6048) {
        int lvl, j;
        if (t < 4608) { lvl = 0; j = t; }
        else if (t < 5760) { lvl = 1; j = t - 4608; }
        else { lvl = 2; j = t - 5760; }
        const int logW = 7 - lvl;
        const int W = 1 << logW, H = W, HW = H * W;
        const int nper = 64 >> (2 * lvl);
        const int qb = j % nper, gk = (j / nper) % 36, b = j / (nper * 36);
        const int g = gk / 9, k = gk - g * 9;
        const float* OFFM = ws + (lvl == 0 ? 0 : (lvl == 1 ? 2359296 : 2949120));
        const float* MOD = ws + (lvl == 0 ? 3096576 : (lvl == 1 ? 4276224 : 4571136));
        const float* XT = p.out + (lvl == 0 ? 655360 : (lvl == 1 ? 131072 : 0));
        unsigned* S = (unsigned*)(ws + 4919232) + (lvl == 0 ? 0 : (lvl == 1 ? 9437184 : 11796480));
        const int q = qb * 256 + threadIdx.x;
        const int h = q >> logW, xp = q & (W - 1);
        const int ky = k / 3, kx = k - ky * 3;
        float dy = OFFM[(size_t)(b * 72 + g * 18 + 2 * k) * HW + q];
        float dx = OFFM[(size_t)(b * 72 + g * 18 + 2 * k + 1) * HW + q];
        float m = MOD[(size_t)(b * 36 + g * 9 + k) * HW + q];
        float py = (float)(h - 1 + ky) + dy;
        float px = (float)(xp - 1 + kx) + dx;
        float y0f = floorf(py), x0f = floorf(px);
        float wy = py - y0f, wx = px - x0f;
        int y0 = (int)y0f, x0 = (int)x0f;
        const float* xg = XT + (size_t)(b * 4 + g) * HW * 16;
        float s[16];
#pragma unroll
        for (int c = 0; c < 16; ++c) s[c] = 0.f;
#pragma unroll
        for (int cor = 0; cor < 4; ++cor) {
            int yy = y0 + (cor >> 1), xx = x0 + (cor & 1);
            float cw = ((cor >> 1) ? wy : 1.f - wy) * ((cor & 1) ? wx : 1.f - wx);
            cw = (yy >= 0 && yy < H && xx >= 0 && xx < W) ? cw * m : 0.f;
            int yc = min(max(yy, 0), H - 1), xc = min(max(xx, 0), W - 1);
            const float4* pp = (const float4*)(xg + (size_t)((yc << logW) + xc) * 16);
            float4 v0 = pp[0], v1 = pp[1], v2 = pp[2], v3 = pp[3];
            s[0] = fmaf(cw, v0.x, s[0]);   s[1] = fmaf(cw, v0.y, s[1]);
            s[2] = fmaf(cw, v0.z, s[2]);   s[3] = fmaf(cw, v0.w, s[3]);
            s[4] = fmaf(cw, v1.x, s[4]);   s[5] = fmaf(cw, v1.y, s[5]);
            s[6] = fmaf(cw, v1.z, s[6]);   s[7] = fmaf(cw, v1.w, s[7]);
            s[8] = fmaf(cw, v2.x, s[8]);   s[9] = fmaf(cw, v2.y, s[9]);
            s[10] = fmaf(cw, v2.z, s[10]); s[11] = fmaf(cw, v2.w, s[11]);
            s[12] = fmaf(cw, v3.x, s[12]); s[13] = fmaf(cw, v3.y, s[13]);
            s[14] = fmaf(cw, v3.z, s[14]); s[15] = fmaf(cw, v3.w, s[15]);
        }
        unsigned* Sp = S + (size_t)(b * 288 + gk * 8) * HW + q;
#pragma unroll
        for (int pr = 0; pr < 8; ++pr) {
            unsigned u = bf16rne(s[2 * pr]) | (bf16rne(s[2 * pr + 1]) << 16);
            Sp[(size_t)pr * HW] = u;
        }
    } else {
        int i = t - 6048;
        int lvl, j;
        if (i < 128) { lvl = 0; j = i; }
        else if (i < 160) { lvl = 1; j = i - 128; }
        else { lvl = 2; j = i - 160; }
        const int HW = 16384 >> (2 * lvl);
        const int nper = 64 >> (2 * lvl);
        const int qb = j % nper, b = j / nper;
        const float* OFFM = ws + (lvl == 0 ? 0 : (lvl == 1 ? 2359296 : 2949120));
        float* MEAN = ws + (lvl == 0 ? 4644864 : (lvl == 1 ? 4710400 : 4726784));
        const int q = qb * 256 + threadIdx.x;
        const float* pp = OFFM + (size_t)b * 72 * HW + q;
        float sy = 0.f, sx = 0.f;
#pragma unroll
        for (int u = 0; u < 36; ++u) {
            sy += pp[(size_t)(2 * u) * HW];
            sx += pp[(size_t)(2 * u + 1) * HW];
        }
        MEAN[(size_t)(b * 2) * HW + q] = sy * (1.f / 36.f);
        MEAN[(size_t)(b * 2 + 1) * HW + q] = sx * (1.f / 36.f);
    }
}

// ---------------- K3: dgemm(672, 2x144-row LDS chunks) + upsample(3072) ---------------
__global__ __launch_bounds__(256) void k3_out(P p) {
    __shared__ unsigned lds[144 * 64];  // 36 KB -> 4 blocks/CU
    const int t = blockIdx.x;
    float* ws = p.ws;
    if (t < 672) {
        int lvl, j;
        if (t < 512) { lvl = 0; j = t; }
        else if (t < 640) { lvl = 1; j = t - 512; }
        else { lvl = 2; j = t - 640; }
        const int HW = 16384 >> (2 * lvl);
        const int nper = 256 >> (2 * lvl);
        const int qb = j % nper, b = j / nper;
        const unsigned* S = (const unsigned*)(ws + 4919232) +
                            (lvl == 0 ? 0 : (lvl == 1 ? 9437184 : 11796480));
        const float* wt = ws + 4730880 + lvl * 62784;
        float* outp = p.out + (lvl == 0 ? 655360 : (lvl == 1 ? 131072 : 0));
        const int q0 = qb * 64;
        const int tid = threadIdx.x;
        const int wvu = __builtin_amdgcn_readfirstlane(tid >> 6);
        const int lane = tid & 63;
        float acc[16];
#pragma unroll
        for (int o = 0; o < 16; ++o) acc[o] = 0.f;
        for (int chk = 0; chk < 2; ++chk) {
            __syncthreads();
            const unsigned* Sb = S + (size_t)(b * 288 + chk * 144) * HW + q0;
            for (int i = tid; i < 144 * 16; i += 256) {
                int r = i >> 4, ch = (i & 15) << 2;
                *(uint4*)&lds[r * 64 + ch] = *(const uint4*)(Sb + (size_t)r * HW + ch);
            }
            __syncthreads();
            const float* wbase = wt + chk * 144 * 128 + wvu * 16;
#pragma unroll 2
            for (int r = 0; r < 144; ++r) {
                unsigned u = lds[r * 64 + lane];
                float flo = __uint_as_float(u << 16);
                float fhi = __uint_as_float(u & 0xFFFF0000u);
                const float* wp = wbase + r * 128;
#pragma unroll
                for (int o = 0; o < 16; ++o) acc[o] = fmaf(flo, wp[o], acc[o]);
#pragma unroll
                for (int o = 0; o < 16; ++o) acc[o] = fmaf(fhi, wp[64 + o], acc[o]);
            }
        }
        float* op = outp + (size_t)(b * 64 + wvu * 16) * HW + q0 + lane;
#pragma unroll
        for (int o = 0; o < 16; ++o) op[(size_t)o * HW] = acc[o];
    } else {
        // upsample: 4 px/thread over flat [lvl][b][c][512][512]
        int i = t - 672;  // 0..3071
        int flat = (i * 256 + (int)threadIdx.x) * 4;
        int lvl = flat >> 20;
        int r = flat & 1048575;
        int b = r >> 19, c = (r >> 18) & 1;
        int pix = r & 262143;
        int yo = pix >> 9, xo = pix & 511;
        const int H = 128 >> lvl, W = H;
        const float* MEAN = ws + (lvl == 0 ? 4644864 : (lvl == 1 ? 4710400 : 4726784));
        const float* m = MEAN + (size_t)(b * 2 + c) * H * W;
        float* o = p.out + (lvl == 0 ? 4849664 : (lvl == 1 ? 3801088 : 2752512)) +
                   ((size_t)(b * 2 + c) * 512 + yo) * 512 + xo;
        const float fs = (float)(4 << lvl);
        const float sc = (float)(H - 1) * (1.f / 511.f);
        float sy = yo * sc;
        int y0 = min((int)sy, H - 2);
        float wy = sy - (float)y0;
        float rr[4];
#pragma unroll
        for (int u = 0; u < 4; ++u) {
            float sx = (float)(xo + u) * sc;
            int x0 = min((int)sx, W - 2);
            float wx = sx - (float)x0;
            float v00 = m[y0 * W + x0], v01 = m[y0 * W + x0 + 1];
            float v10 = m[(y0 + 1) * W + x0], v11 = m[(y0 + 1) * W + x0 + 1];
            float r0 = v00 * (1.f - wy) + v10 * wy;
            float r1 = v01 * (1.f - wy) + v11 * wy;
            rr[u] = (r0 * (1.f - wx) + r1 * wx) * fs;
        }
        *(float4*)o = make_float4(rr[0], rr[1], rr[2], rr[3]);
    }
}

extern "C" void kernel_launch(void* const* d_in, const int* in_sizes, int n_in,
                              void* d_out, int out_size, void* d_ws, size_t ws_size,
                              hipStream_t stream) {
    const float* fin[21];
    for (int i = 0; i < 21; ++i) fin[i] = (const float*)d_in[i];
    P p;
    if (in_sizes[1] == in_sizes[0]) {  // dict order sou1,ref1,sou2,ref2,sou3,ref3
        p.sou0 = fin[0]; p.ref0 = fin[1];
        p.sou1 = fin[2]; p.ref1 = fin[3];
        p.sou2 = fin[4]; p.ref2 = fin[5];
    } else {  // arg order
        p.sou0 = fin[0]; p.sou1 = fin[1]; p.sou2 = fin[2];
        p.ref0 = fin[3]; p.ref1 = fin[4]; p.ref2 = fin[5];
    }
    p.ob0 = fin[7]; p.mb0 = fin[9];
    p.ob1 = fin[12]; p.mb1 = fin[14];
    p.ob2 = fin[17]; p.mb2 = fin[19];
    p.out = (float*)d_out;
    p.ws = (float*)d_ws;

    repack_all<<<dim3(144, 3), 256, 0, stream>>>(
        fin[6], fin[8], fin[10], fin[11], fin[13], fin[15], fin[16], fin[18], fin[20],
        p.ws + 4730880);
    k1_prep<<<dim3(1008), 256, 0, stream>>>(p);
    k2_gather<<<dim3(6216), 256, 0, stream>>>(p);
    k3_out<<<dim3(3744), 256, 0, stream>>>(p);
}

// Round 9
// 318.172 us; speedup vs baseline: 4.6768x; 1.5624x over previous
//
#include <hip/hip_runtime.h>

typedef __attribute__((ext_vector_type(8))) short short8;
typedef __attribute__((ext_vector_type(4))) float f32x4;

__device__ __forceinline__ float sigmoidf_(float x) { return 1.f / (1.f + __expf(-x)); }
__device__ __forceinline__ unsigned bf16rne(float x) {
    unsigned b = __float_as_uint(x);
    return (b + 0x7FFFu + ((b >> 16) & 1u)) >> 16;
}

// ws layout (float words):
//   OFFM:  lvl0 @0 (2359296), lvl1 @2359296 (589824), lvl2 @2949120 (147456)
//   MOD:   lvl0 @3096576 (1179648), lvl1 @4276224 (294912), lvl2 @4571136 (73728)
//   MEAN:  lvl0 @4644864 (65536), lvl1 @4710400 (16384), lvl2 @4726784 (4096)
//   WREP:  @4730880, 3*62784; per lvl: [18432 u32 WB (MFMA B-frags, was float reg)]
//                                      [pad to 36864][5184 off][20736 mod]
//   S:     @4919232 (uints), lvl0 +0, lvl1 +9437184, lvl2 +11796480
// XT lives in d_out's feat region (consumed in K2, overwritten in K3):
//   lvl0 @out+655360, lvl1 @out+131072, lvl2 @out+0

struct P {
    const float *sou0, *sou1, *sou2;
    const float *ref0, *ref1, *ref2;
    const float *ob0, *ob1, *ob2;
    const float *mb0, *mb1, *mb2;
    float* out;
    float* ws;
};

// ---------------- K0: fused weight repack (all levels) --------------------------------
// reg_w -> WB: bf16 pairs in mfma_16x16x32_bf16 B-fragment order.
// B frag: lane n = o0+(lane&15), k = (lane>>4)*8 + j; element j=2jw(+1) -> channel
// c0 = ks*32 + (lane>>4)*8 + 2jw. Global channel c = (g*9+kk)*16+cg matches S's K order.
__global__ __launch_bounds__(256) void repack_all(
    const float* __restrict__ ow0, const float* __restrict__ mw0, const float* __restrict__ rw0,
    const float* __restrict__ ow1, const float* __restrict__ mw1, const float* __restrict__ rw1,
    const float* __restrict__ ow2, const float* __restrict__ mw2, const float* __restrict__ rw2,
    float* __restrict__ dst) {
    const int lvl = blockIdx.y;
    const float* ow = lvl == 0 ? ow0 : (lvl == 1 ? ow1 : ow2);
    const float* mw = lvl == 0 ? mw0 : (lvl == 1 ? mw1 : mw2);
    const float* rw = lvl == 0 ? rw0 : (lvl == 1 ? rw1 : rw2);
    float* d = dst + lvl * 62784;
    int i = blockIdx.x * 256 + threadIdx.x;
    if (i < 18432) {  // WB: ((wvu*18+ks)*64+lane)*4+jw  (u32 = bf16 c0 | bf16 c0+1 <<16)
        int jw = i & 3;
        int lane = (i >> 2) & 63;
        int t3 = i >> 8;
        int ks = t3 % 18, wvu = t3 / 18;
        int o = wvu * 16 + (lane & 15);
        int c0 = ks * 32 + (lane >> 4) * 8 + 2 * jw;
        int g0 = c0 / 144, r0 = c0 % 144;
        int c1 = c0 + 1;
        int g1 = c1 / 144, r1 = c1 % 144;
        float w0 = rw[o * 576 + (g0 * 16 + (r0 & 15)) * 9 + (r0 >> 4)];
        float w1 = rw[o * 576 + (g1 * 16 + (r1 & 15)) * 9 + (r1 >> 4)];
        ((unsigned*)d)[i] = bf16rne(w0) | (bf16rne(w1) << 16);
    }
    if (i < 5184) {   // off -> [ic][k][18]
        int oc = i % 18, k = (i / 18) % 9, ic = i / 162;
        d[36864 + i] = ow[oc * 288 + ic * 9 + k];
    }
    if (i < 20736) {  // mod -> [ic][k][36]
        int oc = i % 36, k = (i / 36) % 9, ic = i / 324;
        d[42048 + i] = mw[oc * 576 + ic * 9 + k];
    }
}

// ---------------- K1: offset_conv(168) + mod_conv(168) + transpose(672) ---------------
// 4 pixels/thread; no launch_bounds (R5/R6: bound w caps VGPR ~256/w -> spills).
__global__ __launch_bounds__(256) void k1_prep(P p) {
    __shared__ float tile[256][17];
    const int t = blockIdx.x;
    int task, i;
    if (t < 168) { task = 0; i = t; }
    else if (t < 336) { task = 1; i = t - 168; }
    else { task = 2; i = t - 336; }
    float* ws = p.ws;

    if (task == 0) {  // ---- offset conv: 32ch(concat) -> 18, sigmoid map, 4 px/thread
        int lvl, j;
        if (i < 128) { lvl = 0; j = i; }
        else if (i < 160) { lvl = 1; j = i - 128; }
        else { lvl = 2; j = i - 160; }
        const int logW = 7 - lvl;
        const int W = 1 << logW, H = W, HW = H * W;
        const int nper = 16 >> (2 * lvl);
        const int qb = j % nper, g = (j / nper) & 3, b = j / (nper * 4);
        const int q = qb * 1024 + (int)threadIdx.x * 4;
        const int h = q >> logW, x0 = q & (W - 1);
        const float* sou = lvl == 0 ? p.sou0 : (lvl == 1 ? p.sou1 : p.sou2);
        const float* ref = lvl == 0 ? p.ref0 : (lvl == 1 ? p.ref1 : p.ref2);
        const float* wt = ws + 4730880 + lvl * 62784 + 36864;
        const float* bias = lvl == 0 ? p.ob0 : (lvl == 1 ? p.ob1 : p.ob2);
        float* OFFM = ws + (lvl == 0 ? 0 : (lvl == 1 ? 2359296 : 2949120));
        const float rng = 0.25f * (float)H;
        float acc[4][18];
#pragma unroll
        for (int px = 0; px < 4; ++px)
#pragma unroll
            for (int u = 0; u < 18; ++u) acc[px][u] = 0.f;
        const float* base_s = sou + (size_t)(b * 64 + g * 16) * HW;
        const float* base_r = ref + (size_t)(b * 64 + g * 16) * HW;
        for (int ic = 0; ic < 32; ++ic) {
            const float* plane = (ic < 16) ? base_s + (size_t)ic * HW
                                           : base_r + (size_t)(ic - 16) * HW;
            const float* wp = wt + ic * 162;
#pragma unroll
            for (int ky = 0; ky < 3; ++ky) {
                int yy = h + ky - 1;
                bool yok = (yy >= 0) && (yy < H);
                const float* row = plane + (size_t)min(max(yy, 0), H - 1) * W;
                float w[6];
                float4 f4 = yok ? *(const float4*)(row + x0) : make_float4(0.f, 0.f, 0.f, 0.f);
                w[0] = (yok && x0 > 0) ? row[x0 - 1] : 0.f;
                w[1] = f4.x; w[2] = f4.y; w[3] = f4.z; w[4] = f4.w;
                w[5] = (yok && x0 + 4 < W) ? row[x0 + 4] : 0.f;
#pragma unroll
                for (int kx = 0; kx < 3; ++kx) {
                    const float* wk = wp + (ky * 3 + kx) * 18;
#pragma unroll
                    for (int oc = 0; oc < 18; ++oc) {
                        float wv = wk[oc];
#pragma unroll
                        for (int px = 0; px < 4; ++px)
                            acc[px][oc] = fmaf(w[px + kx], wv, acc[px][oc]);
                    }
                }
            }
        }
#pragma unroll
        for (int oc = 0; oc < 18; ++oc) {
            float r[4];
#pragma unroll
            for (int px = 0; px < 4; ++px) {
                float v = acc[px][oc] + bias[oc];
                r[px] = rng * (2.f * sigmoidf_(v) - 1.f);
            }
            *(float4*)&OFFM[(size_t)(b * 72 + g * 18 + oc) * HW + q] =
                make_float4(r[0], r[1], r[2], r[3]);
        }
    } else if (task == 1) {  // ---- modulator conv: 64 -> 36, wave oc-split, 4 px/lane
        int lvl, j;
        if (i < 128) { lvl = 0; j = i; }
        else if (i < 160) { lvl = 1; j = i - 128; }
        else { lvl = 2; j = i - 160; }
        const int logW = 7 - lvl;
        const int W = 1 << logW, H = W, HW = H * W;
        const int nper = 64 >> (2 * lvl);
        const int qb = j % nper, b = j / nper;
        const int o0 = __builtin_amdgcn_readfirstlane((int)threadIdx.x >> 6) * 9;
        const int lane = threadIdx.x & 63;
        const int q = qb * 256 + lane * 4;
        const int h = q >> logW, x0 = q & (W - 1);
        const float* sou = lvl == 0 ? p.sou0 : (lvl == 1 ? p.sou1 : p.sou2);
        const float* wt = ws + 4730880 + lvl * 62784 + 42048;
        const float* bias = lvl == 0 ? p.mb0 : (lvl == 1 ? p.mb1 : p.mb2);
        float* MOD = ws + (lvl == 0 ? 3096576 : (lvl == 1 ? 4276224 : 4571136));
        float acc[4][9];
#pragma unroll
        for (int px = 0; px < 4; ++px)
#pragma unroll
            for (int u = 0; u < 9; ++u) acc[px][u] = 0.f;
        const float* base = sou + (size_t)b * 64 * HW;
        for (int ic = 0; ic < 64; ++ic) {
            const float* plane = base + (size_t)ic * HW;
            const float* wp = wt + ic * 324 + o0;
#pragma unroll
            for (int ky = 0; ky < 3; ++ky) {
                int yy = h + ky - 1;
                bool yok = (yy >= 0) && (yy < H);
                const float* row = plane + (size_t)min(max(yy, 0), H - 1) * W;
                float w[6];
                float4 f4 = yok ? *(const float4*)(row + x0) : make_float4(0.f, 0.f, 0.f, 0.f);
                w[0] = (yok && x0 > 0) ? row[x0 - 1] : 0.f;
                w[1] = f4.x; w[2] = f4.y; w[3] = f4.z; w[4] = f4.w;
                w[5] = (yok && x0 + 4 < W) ? row[x0 + 4] : 0.f;
#pragma unroll
                for (int kx = 0; kx < 3; ++kx) {
                    const float* wk = wp + (ky * 3 + kx) * 36;
#pragma unroll
                    for (int oc = 0; oc < 9; ++oc) {
                        float wv = wk[oc];
#pragma unroll
                        for (int px = 0; px < 4; ++px)
                            acc[px][oc] = fmaf(w[px + kx], wv, acc[px][oc]);
                    }
                }
            }
        }
#pragma unroll
        for (int oc = 0; oc < 9; ++oc) {
            float r[4];
#pragma unroll
            for (int px = 0; px < 4; ++px)
                r[px] = 2.f * sigmoidf_(acc[px][oc] + bias[o0 + oc]);
            *(float4*)&MOD[(size_t)(b * 36 + o0 + oc) * HW + q] =
                make_float4(r[0], r[1], r[2], r[3]);
        }
    } else {  // ---- transpose (b,64,H,W) -> XT (b,g,HW,16)
        int lvl, j;
        if (i < 512) { lvl = 0; j = i; }
        else if (i < 640) { lvl = 1; j = i - 512; }
        else { lvl = 2; j = i - 640; }
        const int HW = 16384 >> (2 * lvl);
        const int nper = 64 >> (2 * lvl);
        const int qb = j % nper, g = (j / nper) & 3, b = j / (nper * 4);
        const float* sou = lvl == 0 ? p.sou0 : (lvl == 1 ? p.sou1 : p.sou2);
        float* XT = p.out + (lvl == 0 ? 655360 : (lvl == 1 ? 131072 : 0));
        const int tt = threadIdx.x;
        const int q0 = qb * 256;
        const float* src = sou + (size_t)(b * 64 + g * 16) * HW + q0;
#pragma unroll
        for (int c = 0; c < 16; ++c) tile[tt][c] = src[(size_t)c * HW + tt];
        __syncthreads();
        float4* dst = (float4*)(XT + ((size_t)(b * 4 + g) * HW + q0) * 16);
#pragma unroll
        for (int u = 0; u < 4; ++u) {
            int f4 = u * 256 + tt;
            int q = f4 >> 2, c4 = (f4 & 3) * 4;
            dst[f4] = make_float4(tile[q][c4], tile[q][c4 + 1], tile[q][c4 + 2], tile[q][c4 + 3]);
        }
    }
}

// ---------------- K2: gather(6048) + mean(168) ----------------------------------------
__global__ __launch_bounds__(256) void k2_gather(P p) {
    const int t = blockIdx.x;
    float* ws = p.ws;
    if (t < 6048) {
        int lvl, j;
        if (t < 4608) { lvl = 0; j = t; }
        else if (t < 5760) { lvl = 1; j = t - 4608; }
        else { lvl = 2; j = t - 5760; }
        const int logW = 7 - lvl;
        const int W = 1 << logW, H = W, HW = H * W;
        const int nper = 64 >> (2 * lvl);
        const int qb = j % nper, gk = (j / nper) % 36, b = j / (nper * 36);
        const int g = gk / 9, k = gk - g * 9;
        const float* OFFM = ws + (lvl == 0 ? 0 : (lvl == 1 ? 2359296 : 2949120));
        const float* MOD = ws + (lvl == 0 ? 3096576 : (lvl == 1 ? 4276224 : 4571136));
        const float* XT = p.out + (lvl == 0 ? 655360 : (lvl == 1 ? 131072 : 0));
        unsigned* S = (unsigned*)(ws + 4919232) + (lvl == 0 ? 0 : (lvl == 1 ? 9437184 : 11796480));
        const int q = qb * 256 + threadIdx.x;
        const int h = q >> logW, xp = q & (W - 1);
        const int ky = k / 3, kx = k - ky * 3;
        float dy = OFFM[(size_t)(b * 72 + g * 18 + 2 * k) * HW + q];
        float dx = OFFM[(size_t)(b * 72 + g * 18 + 2 * k + 1) * HW + q];
        float m = MOD[(size_t)(b * 36 + g * 9 + k) * HW + q];
        float py = (float)(h - 1 + ky) + dy;
        float px = (float)(xp - 1 + kx) + dx;
        float y0f = floorf(py), x0f = floorf(px);
        float wy = py - y0f, wx = px - x0f;
        int y0 = (int)y0f, x0 = (int)x0f;
        const float* xg = XT + (size_t)(b * 4 + g) * HW * 16;
        float s[16];
#pragma unroll
        for (int c = 0; c < 16; ++c) s[c] = 0.f;
#pragma unroll
        for (int cor = 0; cor < 4; ++cor) {
            int yy = y0 + (cor >> 1), xx = x0 + (cor & 1);
            float cw = ((cor >> 1) ? wy : 1.f - wy) * ((cor & 1) ? wx : 1.f - wx);
            cw = (yy >= 0 && yy < H && xx >= 0 && xx < W) ? cw * m : 0.f;
            int yc = min(max(yy, 0), H - 1), xc = min(max(xx, 0), W - 1);
            const float4* pp = (const float4*)(xg + (size_t)((yc << logW) + xc) * 16);
            float4 v0 = pp[0], v1 = pp[1], v2 = pp[2], v3 = pp[3];
            s[0] = fmaf(cw, v0.x, s[0]);   s[1] = fmaf(cw, v0.y, s[1]);
            s[2] = fmaf(cw, v0.z, s[2]);   s[3] = fmaf(cw, v0.w, s[3]);
            s[4] = fmaf(cw, v1.x, s[4]);   s[5] = fmaf(cw, v1.y, s[5]);
            s[6] = fmaf(cw, v1.z, s[6]);   s[7] = fmaf(cw, v1.w, s[7]);
            s[8] = fmaf(cw, v2.x, s[8]);   s[9] = fmaf(cw, v2.y, s[9]);
            s[10] = fmaf(cw, v2.z, s[10]); s[11] = fmaf(cw, v2.w, s[11]);
            s[12] = fmaf(cw, v3.x, s[12]); s[13] = fmaf(cw, v3.y, s[13]);
            s[14] = fmaf(cw, v3.z, s[14]); s[15] = fmaf(cw, v3.w, s[15]);
        }
        unsigned* Sp = S + (size_t)(b * 288 + gk * 8) * HW + q;
#pragma unroll
        for (int pr = 0; pr < 8; ++pr) {
            unsigned u = bf16rne(s[2 * pr]) | (bf16rne(s[2 * pr + 1]) << 16);
            Sp[(size_t)pr * HW] = u;
        }
    } else {
        int i = t - 6048;
        int lvl, j;
        if (i < 128) { lvl = 0; j = i; }
        else if (i < 160) { lvl = 1; j = i - 128; }
        else { lvl = 2; j = i - 160; }
        const int HW = 16384 >> (2 * lvl);
        const int nper = 64 >> (2 * lvl);
        const int qb = j % nper, b = j / nper;
        const float* OFFM = ws + (lvl == 0 ? 0 : (lvl == 1 ? 2359296 : 2949120));
        float* MEAN = ws + (lvl == 0 ? 4644864 : (lvl == 1 ? 4710400 : 4726784));
        const int q = qb * 256 + threadIdx.x;
        const float* pp = OFFM + (size_t)b * 72 * HW + q;
        float sy = 0.f, sx = 0.f;
#pragma unroll
        for (int u = 0; u < 36; ++u) {
            sy += pp[(size_t)(2 * u) * HW];
            sx += pp[(size_t)(2 * u + 1) * HW];
        }
        MEAN[(size_t)(b * 2) * HW + q] = sy * (1.f / 36.f);
        MEAN[(size_t)(b * 2 + 1) * HW + q] = sx * (1.f / 36.f);
    }
}

// ---------------- K3: MFMA dgemm(672, 2x144-row LDS chunks) + upsample(3072) ----------
// D[px][o] = sum_c S[c][px] * W[c][o], K=576, via mfma_f32_16x16x32_bf16.
// A: m=lane&15 (px), k=quad*8+j -> 4x ds_read_b32 of lds[r][px] pair rows.
// B: n=lane&15 (o), k=quad*8+j -> one dwordx4 from WB per k-step (repacked).
// D: n=lane&15, m=quad*4+reg.
__global__ __launch_bounds__(256) void k3_out(P p) {
    __shared__ unsigned lds[144 * 64];  // 36 KB -> 4 blocks/CU
    const int t = blockIdx.x;
    float* ws = p.ws;
    if (t < 672) {
        int lvl, j;
        if (t < 512) { lvl = 0; j = t; }
        else if (t < 640) { lvl = 1; j = t - 512; }
        else { lvl = 2; j = t - 640; }
        const int HW = 16384 >> (2 * lvl);
        const int nper = 256 >> (2 * lvl);
        const int qb = j % nper, b = j / nper;
        const unsigned* S = (const unsigned*)(ws + 4919232) +
                            (lvl == 0 ? 0 : (lvl == 1 ? 9437184 : 11796480));
        const unsigned* WB = (const unsigned*)(ws + 4730880 + lvl * 62784);
        float* outp = p.out + (lvl == 0 ? 655360 : (lvl == 1 ? 131072 : 0));
        const int q0 = qb * 64;
        const int tid = threadIdx.x;
        const int wvu = __builtin_amdgcn_readfirstlane(tid >> 6);
        const int lane = tid & 63;
        const int quad = lane >> 4, lo16 = lane & 15;
        union U { uint4 u; int4 i; short8 s; f32x4 f; };
        f32x4 acc[4];
#pragma unroll
        for (int mt = 0; mt < 4; ++mt) acc[mt] = (f32x4){0.f, 0.f, 0.f, 0.f};
        for (int chk = 0; chk < 2; ++chk) {
            __syncthreads();
            const unsigned* Sb = S + (size_t)(b * 288 + chk * 144) * HW + q0;
            for (int i = tid; i < 144 * 16; i += 256) {
                int r = i >> 4, ch = (i & 15) << 2;
                *(uint4*)&lds[r * 64 + ch] = *(const uint4*)(Sb + (size_t)r * HW + ch);
            }
            __syncthreads();
            uint4 bfr[9];
#pragma unroll
            for (int k9 = 0; k9 < 9; ++k9)
                bfr[k9] = *(const uint4*)(WB + (((wvu * 18 + chk * 9 + k9) * 64 + lane) << 2));
#pragma unroll
            for (int k9 = 0; k9 < 9; ++k9) {
                const int rb = k9 * 16 + quad * 4;
                U bu; bu.u = bfr[k9];
#pragma unroll
                for (int mt = 0; mt < 4; ++mt) {
                    const int px = mt * 16 + lo16;
                    U au;
                    au.i.x = (int)lds[(rb + 0) * 64 + px];
                    au.i.y = (int)lds[(rb + 1) * 64 + px];
                    au.i.z = (int)lds[(rb + 2) * 64 + px];
                    au.i.w = (int)lds[(rb + 3) * 64 + px];
                    acc[mt] = __builtin_amdgcn_mfma_f32_16x16x32_bf16(au.s, bu.s, acc[mt], 0, 0, 0);
                }
            }
        }
        float* op = outp + (size_t)(b * 64 + wvu * 16 + lo16) * HW + q0;
#pragma unroll
        for (int mt = 0; mt < 4; ++mt)
#pragma unroll
            for (int rg = 0; rg < 4; ++rg)
                op[mt * 16 + quad * 4 + rg] = acc[mt][rg];
    } else {
        // upsample: 4 px/thread over flat [lvl][b][c][512][512]
        int i = t - 672;  // 0..3071
        int flat = (i * 256 + (int)threadIdx.x) * 4;
        int lvl = flat >> 20;
        int r = flat & 1048575;
        int b = r >> 19, c = (r >> 18) & 1;
        int pix = r & 262143;
        int yo = pix >> 9, xo = pix & 511;
        const int H = 128 >> lvl, W = H;
        const float* MEAN = ws + (lvl == 0 ? 4644864 : (lvl == 1 ? 4710400 : 4726784));
        const float* m = MEAN + (size_t)(b * 2 + c) * H * W;
        float* o = p.out + (lvl == 0 ? 4849664 : (lvl == 1 ? 3801088 : 2752512)) +
                   ((size_t)(b * 2 + c) * 512 + yo) * 512 + xo;
        const float fs = (float)(4 << lvl);
        const float sc = (float)(H - 1) * (1.f / 511.f);
        float sy = yo * sc;
        int y0 = min((int)sy, H - 2);
        float wy = sy - (float)y0;
        float rr[4];
#pragma unroll
        for (int u = 0; u < 4; ++u) {
            float sx = (float)(xo + u) * sc;
            int x0 = min((int)sx, W - 2);
            float wx = sx - (float)x0;
            float v00 = m[y0 * W + x0], v01 = m[y0 * W + x0 + 1];
            float v10 = m[(y0 + 1) * W + x0], v11 = m[(y0 + 1) * W + x0 + 1];
            float r0 = v00 * (1.f - wy) + v10 * wy;
            float r1 = v01 * (1.f - wy) + v11 * wy;
            rr[u] = (r0 * (1.f - wx) + r1 * wx) * fs;
        }
        *(float4*)o = make_float4(rr[0], rr[1], rr[2], rr[3]);
    }
}

extern "C" void kernel_launch(void* const* d_in, const int* in_sizes, int n_in,
                              void* d_out, int out_size, void* d_ws, size_t ws_size,
                              hipStream_t stream) {
    const float* fin[21];
    for (int i = 0; i < 21; ++i) fin[i] = (const float*)d_in[i];
    P p;
    if (in_sizes[1] == in_sizes[0]) {  // dict order sou1,ref1,sou2,ref2,sou3,ref3
        p.sou0 = fin[0]; p.ref0 = fin[1];
        p.sou1 = fin[2]; p.ref1 = fin[3];
        p.sou2 = fin[4]; p.ref2 = fin[5];
    } else {  // arg order
        p.sou0 = fin[0]; p.sou1 = fin[1]; p.sou2 = fin[2];
        p.ref0 = fin[3]; p.ref1 = fin[4]; p.ref2 = fin[5];
    }
    p.ob0 = fin[7]; p.mb0 = fin[9];
    p.ob1 = fin[12]; p.mb1 = fin[14];
    p.ob2 = fin[17]; p.mb2 = fin[19];
    p.out = (float*)d_out;
    p.ws = (float*)d_ws;

    repack_all<<<dim3(144, 3), 256, 0, stream>>>(
        fin[6], fin[8], fin[10], fin[11], fin[13], fin[15], fin[16], fin[18], fin[20],
        p.ws + 4730880);
    k1_prep<<<dim3(1008), 256, 0, stream>>>(p);
    k2_gather<<<dim3(6216), 256, 0, stream>>>(p);
    k3_out<<<dim3(3744), 256, 0, stream>>>(p);
}